// Round 11
// baseline (16900.830 us; speedup 1.0000x reference)
//
#include <hip/hip_runtime.h>
#include <cstdint>

// ---- problem constants ----
#define NT  4
#define NB  32
#define NC  512
#define NCH 2048
#define NN  196
#define NM  (NB * NN)   // 6272 columns = 98*64
#define NMB (NM / 8)    // 784 column-bytes
#define NH  8

struct GP {
    const float *q_bn_s, *q_bn_b, *k_bn_s, *k_bn_b;
    const float *proj_b, *proj_bn_s, *proj_bn_b;
    const float *mlp1_b, *mlp1_bn_s, *mlp1_bn_b;
    const float *mlp2_b, *mlp2_bn_s, *mlp2_bn_b;
    const float *wqkT, *wprojT, *wmlp1T, *wmlp2T;  // [K][O] transposed weights
    const float *xT;                                // [T][C][M] permuted input
    float *xy;                                      // [C][M] x + y_spike (per t)
    float *v_q, *v_k, *v_y, *v_h1, *v_h2, *v_attn;  // LIF states
    // TRANSPOSED bit-planes: [col-byte][channel]  (bit j = column mB*8+j)
    unsigned char *q_bt, *k_bt, *h1_bt, *attn_bt;   // [NMB][512/512/2048/8]
    float *out;
    int t;
};

// Exact-f32 LIF step (bitwise-validated vs reference in R2-R10).
__device__ __forceinline__ float lif_step(float z, float v_old, float vth, int& sp) {
    float d = __fsub_rn(z, v_old);
    float h = __fmul_rn(d, 0.5f);
    float v = __fadd_rn(v_old, h);
    sp = (v >= vth) ? 1 : 0;
    return sp ? 0.0f : v;
}

typedef const void __attribute__((address_space(1))) gas_t;
typedef void __attribute__((address_space(3))) las_t;
__device__ __forceinline__ void gl_lds16(const float* g, float* l) {
    __builtin_amdgcn_global_load_lds((gas_t*)g, (las_t*)l, 16, 0, 0);
}
template <int N>
__device__ __forceinline__ void vmwait() {
    if constexpr (N == 0)      asm volatile("s_waitcnt vmcnt(0)" ::: "memory");
    else if constexpr (N == 3) asm volatile("s_waitcnt vmcnt(3)" ::: "memory");
    else if constexpr (N == 6) asm volatile("s_waitcnt vmcnt(6)" ::: "memory");
}
__device__ __forceinline__ void vm0() {
    asm volatile("s_waitcnt vmcnt(0)" ::: "memory");
}

// ---------------- pre-kernels ----------------

// dst[c*ldD + offD + o] = src[o*K + c]   (32x32 LDS tiles)
__global__ __launch_bounds__(256) void trw_k(const float* __restrict__ src,
                                             float* __restrict__ dst,
                                             int K, int ldD, int offD) {
    __shared__ float tle[32][33];
    const int c0 = blockIdx.x * 32, o0 = blockIdx.y * 32;
    const int tx = threadIdx.x & 31, ty = threadIdx.x >> 5;
#pragma unroll
    for (int r = 0; r < 4; ++r)
        tle[ty + r * 8][tx] = src[(size_t)(o0 + ty + r * 8) * K + c0 + tx];
    __syncthreads();
#pragma unroll
    for (int r = 0; r < 4; ++r)
        dst[(size_t)(c0 + ty + r * 8) * ldD + offD + o0 + tx] = tle[tx][ty + r * 8];
}

// xT[t][c][b][n] = x[t][b][c][n]
__global__ __launch_bounds__(64) void permx_k(const float* __restrict__ x,
                                              float* __restrict__ xT) {
    const int id = blockIdx.x;         // t*16384 + c*32 + b
    const int b = id & 31;
    const int c = (id >> 5) & 511;
    const int t = id >> 14;
    const float* s = x + ((size_t)(t * NB + b) * NC + c) * NN;
    float* d = xT + ((size_t)(t * NC + c) * NB + b) * NN;
    for (int n = threadIdx.x; n < NN; n += 64) d[n] = s[n];
}

// attn LIF: thread = col-byte mB, all 8 heads; SWAR popcount over qT row.
__global__ __launch_bounds__(256) void attn_k(GP gp) {
    const int mB = blockIdx.x * 256 + threadIdx.x;
    if (mB >= NMB) return;
    const unsigned* qr = (const unsigned*)(gp.q_bt + (size_t)mB * NC);  // 128 dwords
    unsigned outB[8];
#pragma unroll
    for (int h = 0; h < NH; ++h) {
        unsigned a[8];
#pragma unroll
        for (int j = 0; j < 8; ++j) a[j] = 0;
#pragma unroll
        for (int d = 0; d < 16; ++d) {
            const unsigned w = qr[h * 16 + d];
#pragma unroll
            for (int j = 0; j < 8; ++j) a[j] += (w >> j) & 0x01010101u;
        }
        float* vr = gp.v_attn + (size_t)h * NM + mB * 8;
        unsigned ob = 0;
#pragma unroll
        for (int j = 0; j < 8; ++j) {
            unsigned s = a[j] + (a[j] >> 16);
            s = (s + (s >> 8)) & 0xff;                   // sum of 64 bits
            float v = gp.t ? vr[j] : 0.0f;
            int sp;
            v = lif_step((float)s, v, 0.5f, sp);          // dyadic-exact
            vr[j] = v;
            ob |= (unsigned)sp << j;
        }
        outB[h] = ob;
    }
    uint2 w;
    w.x = outB[0] | (outB[1] << 8) | (outB[2] << 16) | (outB[3] << 24);
    w.y = outB[4] | (outB[5] << 8) | (outB[6] << 16) | (outB[7] << 24);
    *(uint2*)(gp.attn_bt + (size_t)mB * 8) = w;
}

// ---------------- unfused GEMM + BN + LIF (MODE 0 = q&k, MODE 2 = mlp1) ----------------
// R8-proven: 1 wave/block, 2-buffer wave-private LDS, no barriers, vm0 sync.
template <int MODE>
__global__ __launch_bounds__(64) void gemm_unf(GP gp) {
    constexpr int LDA = (MODE == 0) ? 1024 : 2048;
    constexpr int BK = 16;
    constexpr int NIT = 512 / BK;             // 32

    __shared__ float As[2][BK][32];
    __shared__ float Xs[2][BK][64];

    const int lane = threadIdx.x;
    const int to = lane & 7;
    const int tn = lane >> 3;
    const int m0 = blockIdx.x * 64;
    const int ot = blockIdx.y;
    const int o0 = ot * 32;
    const int mb = m0 + tn * 8;
    const int mbB = (m0 >> 3) + tn;

    const float* wA = (MODE == 0) ? gp.wqkT : gp.wmlp1T;
    const float* xf = (MODE == 0) ? gp.xT + (size_t)gp.t * NC * NM : gp.xy;

    auto stageA = [&](int buf, int s) {
#pragma unroll
        for (int r = 0; r < 2; ++r)
            gl_lds16(wA + (size_t)(s * BK + r * 8 + (lane >> 3)) * LDA + o0 + (lane & 7) * 4,
                     &As[buf][r * 8][0]);
    };
    auto stageX = [&](int buf, int s) {
#pragma unroll
        for (int r = 0; r < 4; ++r)
            gl_lds16(xf + (size_t)(s * BK + r * 4 + (lane >> 4)) * NM + m0 + (lane & 15) * 4,
                     &Xs[buf][r * 4][0]);
    };

    float acc[4][8];
#pragma unroll
    for (int i = 0; i < 4; ++i)
#pragma unroll
        for (int j = 0; j < 8; ++j) acc[i][j] = 0.0f;

    auto compute = [&](int cur) {
#pragma unroll 4
        for (int kk = 0; kk < BK; ++kk) {
            const float4 av = *(const float4*)&As[cur][kk][to * 4];
            const float4 x0 = *(const float4*)&Xs[cur][kk][tn * 8];
            const float4 x1 = *(const float4*)&Xs[cur][kk][tn * 8 + 4];
            const float a4[4] = {av.x, av.y, av.z, av.w};
            const float x8[8] = {x0.x, x0.y, x0.z, x0.w, x1.x, x1.y, x1.z, x1.w};
#pragma unroll
            for (int i = 0; i < 4; ++i)
#pragma unroll
                for (int j = 0; j < 8; ++j)
                    acc[i][j] = __fadd_rn(acc[i][j], __fmul_rn(a4[i], x8[j]));
        }
    };

    stageA(0, 0); stageX(0, 0);
    vm0();
#pragma unroll 1
    for (int it = 0; it < NIT; ++it) {
        const int cur = it & 1;
        const bool more = (it + 1 < NIT);
        if (more) { stageA(cur ^ 1, it + 1); stageX(cur ^ 1, it + 1); }
        compute(cur);
        if (more) vm0();
    }

    // epilogue: BN + LIF; bits go to TRANSPOSED planes (u32 = 4 consecutive o)
    if constexpr (MODE == 0) {
        const bool isq = (ot < 16);
        const float* bs = isq ? gp.q_bn_s : gp.k_bn_s;
        const float* bbv = isq ? gp.q_bn_b : gp.k_bn_b;
        float* vb = isq ? gp.v_q : gp.v_k;
        unsigned char* sb = isq ? gp.q_bt : gp.k_bt;
        const int ob = (ot & 15) * 32;
        unsigned pw = 0;
#pragma unroll
        for (int i = 0; i < 4; ++i) {
            const int oo = ob + to * 4 + i;
            const float sc = bs[oo], bc = bbv[oo];
            float* vr = vb + (size_t)oo * NM + mb;
            float vv[8];
            if (gp.t) {
                const float4 v0 = *(const float4*)vr, v1 = *(const float4*)(vr + 4);
                vv[0] = v0.x; vv[1] = v0.y; vv[2] = v0.z; vv[3] = v0.w;
                vv[4] = v1.x; vv[5] = v1.y; vv[6] = v1.z; vv[7] = v1.w;
            } else {
#pragma unroll
                for (int j = 0; j < 8; ++j) vv[j] = 0.0f;
            }
            unsigned pb = 0;
#pragma unroll
            for (int j = 0; j < 8; ++j) {
                const float z = __fadd_rn(__fmul_rn(acc[i][j], sc), bc);
                int sp;
                vv[j] = lif_step(z, vv[j], 1.0f, sp);
                pb |= (unsigned)sp << j;
            }
            *(float4*)vr = make_float4(vv[0], vv[1], vv[2], vv[3]);
            *(float4*)(vr + 4) = make_float4(vv[4], vv[5], vv[6], vv[7]);
            pw |= pb << (i * 8);
        }
        *(unsigned*)(sb + (size_t)mbB * NC + ob + to * 4) = pw;
    } else {
        const int ob = ot * 32;
        unsigned pw = 0;
#pragma unroll
        for (int i = 0; i < 4; ++i) {
            const int o = ob + to * 4 + i;
            const float bi = gp.mlp1_b[o], sc = gp.mlp1_bn_s[o], bc = gp.mlp1_bn_b[o];
            float* vr = gp.v_h1 + (size_t)o * NM + mb;
            float vv[8];
            if (gp.t) {
                const float4 v0 = *(const float4*)vr, v1 = *(const float4*)(vr + 4);
                vv[0] = v0.x; vv[1] = v0.y; vv[2] = v0.z; vv[3] = v0.w;
                vv[4] = v1.x; vv[5] = v1.y; vv[6] = v1.z; vv[7] = v1.w;
            } else {
#pragma unroll
                for (int j = 0; j < 8; ++j) vv[j] = 0.0f;
            }
            unsigned pb = 0;
#pragma unroll
            for (int j = 0; j < 8; ++j) {
                const float z = __fadd_rn(__fmul_rn(__fadd_rn(acc[i][j], bi), sc), bc);
                int sp;
                vv[j] = lif_step(z, vv[j], 1.0f, sp);
                pb |= (unsigned)sp << j;
            }
            *(float4*)vr = make_float4(vv[0], vv[1], vv[2], vv[3]);
            *(float4*)(vr + 4) = make_float4(vv[4], vv[5], vv[6], vv[7]);
            pw |= pb << (i * 8);
        }
        *(unsigned*)(gp.h1_bt + (size_t)mbB * NCH + ob + to * 4) = pw;
    }
}

// ---------------- fused GEMM + BN + LIF (MODE 1 = proj, MODE 3 = mlp2) ----------------
// A in LDS (0.5 B/FMA -> not LDS-bound), X = bit-plane in REGISTERS
// (per-thread byte-column stream, dwordx4 per 16 c). 4-buffer A ring,
// stage-ahead 2, counted vmcnt(6) (3 VM ops/stage). No barriers.
template <int MODE>
__global__ __launch_bounds__(64) void gemm_fus(GP gp) {
    constexpr int K_TOT = (MODE == 3) ? 2048 : 512;
    constexpr int BK = 16;
    constexpr int NIT = K_TOT / BK;           // 32 or 128 (mult of 4)

    __shared__ float As[4][BK][32];           // 8 KB total

    const int lane = threadIdx.x;
    const int to = lane & 7;                  // 4 rows each
    const int tn = lane >> 3;                 // 8 cols each
    const int m0 = blockIdx.x * 64;
    const int o0 = blockIdx.y * 32;
    const int mb = m0 + tn * 8;
    const int mB = (m0 >> 3) + tn;

    const float* wA = (MODE == 1) ? gp.wprojT : gp.wmlp2T;
    const unsigned char* xbt = (MODE == 1) ? gp.k_bt : gp.h1_bt;

    uint2 aU2 = {0, 0};
    if constexpr (MODE == 1) {
        aU2 = *(const uint2*)(gp.attn_bt + (size_t)mB * 8);
        vm0();                                // settle before vmcnt bookkeeping
    }

    auto stageA = [&](int buf, int s) {
#pragma unroll
        for (int r = 0; r < 2; ++r)
            gl_lds16(wA + (size_t)(s * BK + r * 8 + (lane >> 3)) * 512 + o0 + (lane & 7) * 4,
                     &As[buf][r * 8][0]);
    };
    auto loadK = [&](int s) -> uint4 {
        return *(const uint4*)(xbt + (size_t)mB * K_TOT + s * BK);
    };

    float acc[4][8];
#pragma unroll
    for (int i = 0; i < 4; ++i)
#pragma unroll
        for (int j = 0; j < 8; ++j) acc[i][j] = 0.0f;

    auto compute = [&](int cb, uint4 kb, int it) {
        unsigned dw[4] = {kb.x, kb.y, kb.z, kb.w};
        if constexpr (MODE == 1) {
            const int h = it >> 2;            // 64 c per head, 16 c per iter
            const unsigned ab = ((h < 4) ? (aU2.x >> (h * 8)) : (aU2.y >> ((h - 4) * 8))) & 0xffu;
            const unsigned ar = ab * 0x01010101u;
#pragma unroll
            for (int q = 0; q < 4; ++q) dw[q] &= ar;   // x_one = k & attn (exact)
        }
#pragma unroll
        for (int kk = 0; kk < BK; ++kk) {
            const float4 av = *(const float4*)&As[cb][kk][to * 4];
            const float a4[4] = {av.x, av.y, av.z, av.w};
            const unsigned bsel = dw[kk >> 2] >> ((kk & 3) * 8);
            float x8[8];
#pragma unroll
            for (int j = 0; j < 8; ++j) x8[j] = (float)((bsel >> j) & 1u);
#pragma unroll
            for (int i = 0; i < 4; ++i)
#pragma unroll
                for (int j = 0; j < 8; ++j)
                    acc[i][j] = __fmaf_rn(a4[i], x8[j], acc[i][j]);
        }
    };

    uint4 s0, s1, s2, s3;
    stageA(0, 0); s0 = loadK(0);
    stageA(1, 1); s1 = loadK(1);

#pragma unroll 1
    for (int i = 0; i + 4 < NIT; i += 4) {
        stageA(2, i + 2); s2 = loadK(i + 2); vmwait<6>(); compute(0, s0, i + 0);
        stageA(3, i + 3); s3 = loadK(i + 3); vmwait<6>(); compute(1, s1, i + 1);
        stageA(0, i + 4); s0 = loadK(i + 4); vmwait<6>(); compute(2, s2, i + 2);
        stageA(1, i + 5); s1 = loadK(i + 5); vmwait<6>(); compute(3, s3, i + 3);
    }
    {   // peel: last 4 iters (NIT-4 .. NIT-1)
        stageA(2, NIT - 2); s2 = loadK(NIT - 2); vmwait<6>(); compute(0, s0, NIT - 4);
        stageA(3, NIT - 1); s3 = loadK(NIT - 1); vmwait<6>(); compute(1, s1, NIT - 3);
        vmwait<3>(); compute(2, s2, NIT - 2);
        vmwait<0>(); compute(3, s3, NIT - 1);
    }

    // ---- epilogue: BN + LIF, exact reference op order (4 rows x 8 cols) ----
    if constexpr (MODE == 1) {
#pragma unroll
        for (int i = 0; i < 4; ++i) {
            const int o = o0 + to * 4 + i;
            const float bi = gp.proj_b[o], sc = gp.proj_bn_s[o], bc = gp.proj_bn_b[o];
            float* vr = gp.v_y + (size_t)o * NM + mb;
            const float* xr = gp.xT + ((size_t)gp.t * NC + o) * NM + mb;
            float* xyr = gp.xy + (size_t)o * NM + mb;
#pragma unroll
            for (int half = 0; half < 2; ++half) {
                const float4 vld = gp.t ? *(const float4*)(vr + half * 4) : make_float4(0, 0, 0, 0);
                const float4 xv4 = *(const float4*)(xr + half * 4);
                float vv[4] = {vld.x, vld.y, vld.z, vld.w};
                const float xvv[4] = {xv4.x, xv4.y, xv4.z, xv4.w};
                float xyo[4];
#pragma unroll
                for (int j = 0; j < 4; ++j) {
                    const float z = __fadd_rn(__fmul_rn(__fadd_rn(acc[i][half * 4 + j], bi), sc), bc);
                    int sp;
                    vv[j] = lif_step(z, vv[j], 1.0f, sp);
                    xyo[j] = __fadd_rn(xvv[j], (float)sp);   // residual x + y
                }
                *(float4*)(vr + half * 4) = make_float4(vv[0], vv[1], vv[2], vv[3]);
                *(float4*)(xyr + half * 4) = make_float4(xyo[0], xyo[1], xyo[2], xyo[3]);
            }
        }
    } else {  // MODE 3
        // 4-aligned halves never straddle a batch boundary (196 % 4 == 0)
        const int b0 = mb / NN,       n0 = mb - b0 * NN;
        const int b1 = (mb + 4) / NN, n1 = (mb + 4) - b1 * NN;
#pragma unroll
        for (int i = 0; i < 4; ++i) {
            const int o = o0 + to * 4 + i;
            const float bi = gp.mlp2_b[o], sc = gp.mlp2_bn_s[o], bc = gp.mlp2_bn_b[o];
            float* vr = gp.v_h2 + (size_t)o * NM + mb;
            const float* xyr = gp.xy + (size_t)o * NM + mb;
#pragma unroll
            for (int half = 0; half < 2; ++half) {
                const float4 vld = gp.t ? *(const float4*)(vr + half * 4) : make_float4(0, 0, 0, 0);
                const float4 xyv = *(const float4*)(xyr + half * 4);
                float vv[4] = {vld.x, vld.y, vld.z, vld.w};
                const float xyf[4] = {xyv.x, xyv.y, xyv.z, xyv.w};
                float ov[4];
#pragma unroll
                for (int j = 0; j < 4; ++j) {
                    const float z = __fadd_rn(__fmul_rn(__fadd_rn(acc[i][half * 4 + j], bi), sc), bc);
                    int sp;
                    vv[j] = lif_step(z, vv[j], 1.0f, sp);
                    ov[j] = __fadd_rn(xyf[j], (float)sp);
                }
                const int b = half ? b1 : b0;
                const int n = half ? n1 : n0;
                *(float4*)&gp.out[(((size_t)gp.t * NB + b) * NC + o) * NN + n] =
                    make_float4(ov[0], ov[1], ov[2], ov[3]);
                *(float4*)(vr + half * 4) = make_float4(vv[0], vv[1], vv[2], vv[3]);
            }
        }
    }
}

extern "C" void kernel_launch(void* const* d_in, const int* in_sizes, int n_in,
                              void* d_out, int out_size, void* d_ws, size_t ws_size,
                              hipStream_t stream) {
    const float* x       = (const float*)d_in[0];
    const float* q_w     = (const float*)d_in[1];
    const float* k_w     = (const float*)d_in[4];
    const float* proj_w  = (const float*)d_in[7];
    const float* mlp1_w  = (const float*)d_in[11];
    const float* mlp2_w  = (const float*)d_in[15];

    GP gp;
    gp.q_bn_s = (const float*)d_in[2];  gp.q_bn_b = (const float*)d_in[3];
    gp.k_bn_s = (const float*)d_in[5];  gp.k_bn_b = (const float*)d_in[6];
    gp.proj_b = (const float*)d_in[8];  gp.proj_bn_s = (const float*)d_in[9];  gp.proj_bn_b = (const float*)d_in[10];
    gp.mlp1_b = (const float*)d_in[12]; gp.mlp1_bn_s = (const float*)d_in[13]; gp.mlp1_bn_b = (const float*)d_in[14];
    gp.mlp2_b = (const float*)d_in[16]; gp.mlp2_bn_s = (const float*)d_in[17]; gp.mlp2_bn_b = (const float*)d_in[18];
    gp.out = (float*)d_out;

    char* ws = (char*)d_ws;
    size_t off = 0;
    auto alloc = [&](size_t bytes) -> void* {
        void* r = ws + off;
        off += (bytes + 255) & ~(size_t)255;
        return r;
    };
    float* wqkT   = (float*)alloc((size_t)512 * 1024 * 4);
    float* wprojT = (float*)alloc((size_t)512 * 512 * 4);
    float* wmlp1T = (float*)alloc((size_t)512 * 2048 * 4);
    float* wmlp2T = (float*)alloc((size_t)2048 * 512 * 4);
    float* xT     = (float*)alloc((size_t)NT * NC * NM * 4);
    gp.xy     = (float*)alloc((size_t)NC * NM * 4);
    gp.v_q    = (float*)alloc((size_t)NC * NM * 4);
    gp.v_k    = (float*)alloc((size_t)NC * NM * 4);
    gp.v_y    = (float*)alloc((size_t)NC * NM * 4);
    gp.v_h2   = (float*)alloc((size_t)NC * NM * 4);
    gp.v_h1   = (float*)alloc((size_t)NCH * NM * 4);
    gp.v_attn = (float*)alloc((size_t)NH * NM * 4);
    gp.q_bt   = (unsigned char*)alloc((size_t)NMB * NC);
    gp.k_bt   = (unsigned char*)alloc((size_t)NMB * NC);
    gp.h1_bt  = (unsigned char*)alloc((size_t)NMB * NCH);
    gp.attn_bt= (unsigned char*)alloc((size_t)NMB * NH);
    gp.wqkT = wqkT; gp.wprojT = wprojT; gp.wmlp1T = wmlp1T; gp.wmlp2T = wmlp2T;
    gp.xT = xT;

    // one-time (per call) layout transforms
    trw_k<<<dim3(16, 16), 256, 0, stream>>>(q_w,    wqkT,   512,  1024, 0);
    trw_k<<<dim3(16, 16), 256, 0, stream>>>(k_w,    wqkT,   512,  1024, 512);
    trw_k<<<dim3(16, 16), 256, 0, stream>>>(proj_w, wprojT, 512,  512,  0);
    trw_k<<<dim3(16, 64), 256, 0, stream>>>(mlp1_w, wmlp1T, 512,  2048, 0);
    trw_k<<<dim3(64, 16), 256, 0, stream>>>(mlp2_w, wmlp2T, 2048, 512,  0);
    permx_k<<<NT * NC * NB, 64, 0, stream>>>(x, xT);

    for (int t = 0; t < NT; ++t) {
        gp.t = t;
        gemm_unf<0><<<dim3(98, 32), 64, 0, stream>>>(gp);   // q,k -> bit-planes
        attn_k<<<dim3(4), 256, 0, stream>>>(gp);            // attn LIF -> bit-plane
        gemm_fus<1><<<dim3(98, 16), 64, 0, stream>>>(gp);   // proj -> v_y, xy
        gemm_unf<2><<<dim3(98, 64), 64, 0, stream>>>(gp);   // mlp1 -> h1 bit-plane
        gemm_fus<3><<<dim3(98, 16), 64, 0, stream>>>(gp);   // mlp2 -> out
    }
}

// Round 12
// 15503.809 us; speedup vs baseline: 1.0901x; 1.0901x over previous
//
#include <hip/hip_runtime.h>
#include <cstdint>

// ---- problem constants ----
#define NT  4
#define NB  32
#define NC  512
#define NCH 2048
#define NN  196
#define NM  (NB * NN)   // 6272 columns = 98*64
#define NMB (NM / 8)    // 784 column-bytes
#define NH  8

struct GP {
    const float *q_bn_s, *q_bn_b, *k_bn_s, *k_bn_b;
    const float *proj_b, *proj_bn_s, *proj_bn_b;
    const float *mlp1_b, *mlp1_bn_s, *mlp1_bn_b;
    const float *mlp2_b, *mlp2_bn_s, *mlp2_bn_b;
    const float *wqkT, *wprojT, *wmlp1T, *wmlp2T;  // [K][O] transposed weights
    const float *xT;                                // [T][C][M] permuted input
    float *xy;                                      // [C][M] x + y_spike (per t)
    float *v_q, *v_k, *v_y, *v_h1, *v_h2, *v_attn;  // LIF states
    // TRANSPOSED bit-planes: [col-byte][channel]  (bit j = column mB*8+j)
    unsigned char *q_bt, *k_bt, *h1_bt, *attn_bt;   // [NMB][512/512/2048/8]
    float *out;
    int t;
};

// Exact-f32 LIF step (bitwise-validated vs reference in R2-R11).
__device__ __forceinline__ float lif_step(float z, float v_old, float vth, int& sp) {
    float d = __fsub_rn(z, v_old);
    float h = __fmul_rn(d, 0.5f);
    float v = __fadd_rn(v_old, h);
    sp = (v >= vth) ? 1 : 0;
    return sp ? 0.0f : v;
}

typedef const void __attribute__((address_space(1))) gas_t;
typedef void __attribute__((address_space(3))) las_t;
__device__ __forceinline__ void gl_lds16(const float* g, float* l) {
    __builtin_amdgcn_global_load_lds((gas_t*)g, (las_t*)l, 16, 0, 0);
}
__device__ __forceinline__ void vm0() {
    asm volatile("s_waitcnt vmcnt(0)" ::: "memory");
}

// ---------------- pre-kernels ----------------

// dst[c*ldD + offD + o] = src[o*K + c]   (32x32 LDS tiles)
__global__ __launch_bounds__(256) void trw_k(const float* __restrict__ src,
                                             float* __restrict__ dst,
                                             int K, int ldD, int offD) {
    __shared__ float tle[32][33];
    const int c0 = blockIdx.x * 32, o0 = blockIdx.y * 32;
    const int tx = threadIdx.x & 31, ty = threadIdx.x >> 5;
#pragma unroll
    for (int r = 0; r < 4; ++r)
        tle[ty + r * 8][tx] = src[(size_t)(o0 + ty + r * 8) * K + c0 + tx];
    __syncthreads();
#pragma unroll
    for (int r = 0; r < 4; ++r)
        dst[(size_t)(c0 + ty + r * 8) * ldD + offD + o0 + tx] = tle[tx][ty + r * 8];
}

// xT[t][c][b][n] = x[t][b][c][n]
__global__ __launch_bounds__(64) void permx_k(const float* __restrict__ x,
                                              float* __restrict__ xT) {
    const int id = blockIdx.x;         // t*16384 + c*32 + b
    const int b = id & 31;
    const int c = (id >> 5) & 511;
    const int t = id >> 14;
    const float* s = x + ((size_t)(t * NB + b) * NC + c) * NN;
    float* d = xT + ((size_t)(t * NC + c) * NB + b) * NN;
    for (int n = threadIdx.x; n < NN; n += 64) d[n] = s[n];
}

// attn LIF: thread = col-byte mB, all 8 heads; SWAR popcount over qT row.
__global__ __launch_bounds__(256) void attn_k(GP gp) {
    const int mB = blockIdx.x * 256 + threadIdx.x;
    if (mB >= NMB) return;
    const unsigned* qr = (const unsigned*)(gp.q_bt + (size_t)mB * NC);  // 128 dwords
    unsigned outB[8];
#pragma unroll
    for (int h = 0; h < NH; ++h) {
        unsigned a[8];
#pragma unroll
        for (int j = 0; j < 8; ++j) a[j] = 0;
#pragma unroll
        for (int d = 0; d < 16; ++d) {
            const unsigned w = qr[h * 16 + d];
#pragma unroll
            for (int j = 0; j < 8; ++j) a[j] += (w >> j) & 0x01010101u;
        }
        float* vr = gp.v_attn + (size_t)h * NM + mB * 8;
        unsigned ob = 0;
#pragma unroll
        for (int j = 0; j < 8; ++j) {
            unsigned s = a[j] + (a[j] >> 16);
            s = (s + (s >> 8)) & 0xff;                   // sum of 64 bits
            float v = gp.t ? vr[j] : 0.0f;
            int sp;
            v = lif_step((float)s, v, 0.5f, sp);          // dyadic-exact
            vr[j] = v;
            ob |= (unsigned)sp << j;
        }
        outB[h] = ob;
    }
    uint2 w;
    w.x = outB[0] | (outB[1] << 8) | (outB[2] << 16) | (outB[3] << 24);
    w.y = outB[4] | (outB[5] << 8) | (outB[6] << 16) | (outB[7] << 24);
    *(uint2*)(gp.attn_bt + (size_t)mB * 8) = w;
}

// ---------------- unfused GEMM + BN + LIF (MODE 0 = q&k, MODE 2 = mlp1) ----------------
// R8-proven: 1 wave/block, 2-buffer wave-private LDS, no barriers, vm0 sync.
template <int MODE>
__global__ __launch_bounds__(64) void gemm_unf(GP gp) {
    constexpr int LDA = (MODE == 0) ? 1024 : 2048;
    constexpr int BK = 16;
    constexpr int NIT = 512 / BK;             // 32

    __shared__ float As[2][BK][32];
    __shared__ float Xs[2][BK][64];

    const int lane = threadIdx.x;
    const int to = lane & 7;
    const int tn = lane >> 3;
    const int m0 = blockIdx.x * 64;
    const int ot = blockIdx.y;
    const int o0 = ot * 32;
    const int mb = m0 + tn * 8;
    const int mbB = (m0 >> 3) + tn;

    const float* wA = (MODE == 0) ? gp.wqkT : gp.wmlp1T;
    const float* xf = (MODE == 0) ? gp.xT + (size_t)gp.t * NC * NM : gp.xy;

    auto stageA = [&](int buf, int s) {
#pragma unroll
        for (int r = 0; r < 2; ++r)
            gl_lds16(wA + (size_t)(s * BK + r * 8 + (lane >> 3)) * LDA + o0 + (lane & 7) * 4,
                     &As[buf][r * 8][0]);
    };
    auto stageX = [&](int buf, int s) {
#pragma unroll
        for (int r = 0; r < 4; ++r)
            gl_lds16(xf + (size_t)(s * BK + r * 4 + (lane >> 4)) * NM + m0 + (lane & 15) * 4,
                     &Xs[buf][r * 4][0]);
    };

    float acc[4][8];
#pragma unroll
    for (int i = 0; i < 4; ++i)
#pragma unroll
        for (int j = 0; j < 8; ++j) acc[i][j] = 0.0f;

    auto compute = [&](int cur) {
#pragma unroll 4
        for (int kk = 0; kk < BK; ++kk) {
            const float4 av = *(const float4*)&As[cur][kk][to * 4];
            const float4 x0 = *(const float4*)&Xs[cur][kk][tn * 8];
            const float4 x1 = *(const float4*)&Xs[cur][kk][tn * 8 + 4];
            const float a4[4] = {av.x, av.y, av.z, av.w};
            const float x8[8] = {x0.x, x0.y, x0.z, x0.w, x1.x, x1.y, x1.z, x1.w};
#pragma unroll
            for (int i = 0; i < 4; ++i)
#pragma unroll
                for (int j = 0; j < 8; ++j)
                    acc[i][j] = __fadd_rn(acc[i][j], __fmul_rn(a4[i], x8[j]));
        }
    };

    stageA(0, 0); stageX(0, 0);
    vm0();
#pragma unroll 1
    for (int it = 0; it < NIT; ++it) {
        const int cur = it & 1;
        const bool more = (it + 1 < NIT);
        if (more) { stageA(cur ^ 1, it + 1); stageX(cur ^ 1, it + 1); }
        compute(cur);
        if (more) vm0();
    }

    // epilogue: BN + LIF; bits go to TRANSPOSED planes (u32 = 4 consecutive o)
    if constexpr (MODE == 0) {
        const bool isq = (ot < 16);
        const float* bs = isq ? gp.q_bn_s : gp.k_bn_s;
        const float* bbv = isq ? gp.q_bn_b : gp.k_bn_b;
        float* vb = isq ? gp.v_q : gp.v_k;
        unsigned char* sb = isq ? gp.q_bt : gp.k_bt;
        const int ob = (ot & 15) * 32;
        unsigned pw = 0;
#pragma unroll
        for (int i = 0; i < 4; ++i) {
            const int oo = ob + to * 4 + i;
            const float sc = bs[oo], bc = bbv[oo];
            float* vr = vb + (size_t)oo * NM + mb;
            float vv[8];
            if (gp.t) {
                const float4 v0 = *(const float4*)vr, v1 = *(const float4*)(vr + 4);
                vv[0] = v0.x; vv[1] = v0.y; vv[2] = v0.z; vv[3] = v0.w;
                vv[4] = v1.x; vv[5] = v1.y; vv[6] = v1.z; vv[7] = v1.w;
            } else {
#pragma unroll
                for (int j = 0; j < 8; ++j) vv[j] = 0.0f;
            }
            unsigned pb = 0;
#pragma unroll
            for (int j = 0; j < 8; ++j) {
                const float z = __fadd_rn(__fmul_rn(acc[i][j], sc), bc);
                int sp;
                vv[j] = lif_step(z, vv[j], 1.0f, sp);
                pb |= (unsigned)sp << j;
            }
            *(float4*)vr = make_float4(vv[0], vv[1], vv[2], vv[3]);
            *(float4*)(vr + 4) = make_float4(vv[4], vv[5], vv[6], vv[7]);
            pw |= pb << (i * 8);
        }
        *(unsigned*)(sb + (size_t)mbB * NC + ob + to * 4) = pw;
    } else {
        const int ob = ot * 32;
        unsigned pw = 0;
#pragma unroll
        for (int i = 0; i < 4; ++i) {
            const int o = ob + to * 4 + i;
            const float bi = gp.mlp1_b[o], sc = gp.mlp1_bn_s[o], bc = gp.mlp1_bn_b[o];
            float* vr = gp.v_h1 + (size_t)o * NM + mb;
            float vv[8];
            if (gp.t) {
                const float4 v0 = *(const float4*)vr, v1 = *(const float4*)(vr + 4);
                vv[0] = v0.x; vv[1] = v0.y; vv[2] = v0.z; vv[3] = v0.w;
                vv[4] = v1.x; vv[5] = v1.y; vv[6] = v1.z; vv[7] = v1.w;
            } else {
#pragma unroll
                for (int j = 0; j < 8; ++j) vv[j] = 0.0f;
            }
            unsigned pb = 0;
#pragma unroll
            for (int j = 0; j < 8; ++j) {
                const float z = __fadd_rn(__fmul_rn(__fadd_rn(acc[i][j], bi), sc), bc);
                int sp;
                vv[j] = lif_step(z, vv[j], 1.0f, sp);
                pb |= (unsigned)sp << j;
            }
            *(float4*)vr = make_float4(vv[0], vv[1], vv[2], vv[3]);
            *(float4*)(vr + 4) = make_float4(vv[4], vv[5], vv[6], vv[7]);
            pw |= pb << (i * 8);
        }
        *(unsigned*)(gp.h1_bt + (size_t)mbB * NCH + ob + to * 4) = pw;
    }
}

// ---------------- fused GEMM + BN + LIF (MODE 1 = proj, MODE 3 = mlp2) ----------------
// A in LDS (2-buffer, 0.5 B/FMA), X = bit-plane in REGISTERS (1 dwordx4/iter,
// L2-resident stream). R11's 4-deep ring spilled (VGPR 44, 800MB scratch);
// this is the R8-proven shallow pipeline: 1-ahead, named kA/kB slots,
// unroll-2 for static indices, plain vm0. Live set ~60 VGPR.
template <int MODE>
__global__ __launch_bounds__(64) void gemm_fus(GP gp) {
    constexpr int K_TOT = (MODE == 3) ? 2048 : 512;
    constexpr int BK = 16;
    constexpr int NIT = K_TOT / BK;           // 32 or 128 (even)

    __shared__ float As[2][BK][32];           // 4 KB

    const int lane = threadIdx.x;
    const int to = lane & 7;                  // 4 rows each
    const int tn = lane >> 3;                 // 8 cols each
    const int m0 = blockIdx.x * 64;
    const int o0 = blockIdx.y * 32;
    const int mb = m0 + tn * 8;
    const int mB = (m0 >> 3) + tn;

    const float* wA = (MODE == 1) ? gp.wprojT : gp.wmlp2T;
    const unsigned char* xbt = (MODE == 1) ? gp.k_bt : gp.h1_bt;

    uint2 aU2 = {0, 0};
    if constexpr (MODE == 1)
        aU2 = *(const uint2*)(gp.attn_bt + (size_t)mB * 8);

    auto stageA = [&](int buf, int s) {
#pragma unroll
        for (int r = 0; r < 2; ++r)
            gl_lds16(wA + (size_t)(s * BK + r * 8 + (lane >> 3)) * 512 + o0 + (lane & 7) * 4,
                     &As[buf][r * 8][0]);
    };
    auto loadK = [&](int s) -> uint4 {
        return *(const uint4*)(xbt + (size_t)mB * K_TOT + s * BK);
    };

    float acc[4][8];
#pragma unroll
    for (int i = 0; i < 4; ++i)
#pragma unroll
        for (int j = 0; j < 8; ++j) acc[i][j] = 0.0f;

    auto compute = [&](int cb, uint4 kb, int it) {
        unsigned dw[4] = {kb.x, kb.y, kb.z, kb.w};
        if constexpr (MODE == 1) {
            const int h = it >> 2;            // 64 c per head, 16 c per iter
            const unsigned ab = ((h < 4) ? (aU2.x >> (h * 8)) : (aU2.y >> ((h - 4) * 8))) & 0xffu;
            const unsigned ar = ab * 0x01010101u;
#pragma unroll
            for (int q = 0; q < 4; ++q) dw[q] &= ar;   // x_one = k & attn (exact)
        }
#pragma unroll
        for (int kk = 0; kk < BK; ++kk) {
            const float4 av = *(const float4*)&As[cb][kk][to * 4];
            const float a4[4] = {av.x, av.y, av.z, av.w};
            const unsigned bsel = dw[kk >> 2] >> ((kk & 3) * 8);
            float x8[8];
#pragma unroll
            for (int j = 0; j < 8; ++j) x8[j] = (float)((bsel >> j) & 1u);
#pragma unroll
            for (int i = 0; i < 4; ++i)
#pragma unroll
                for (int j = 0; j < 8; ++j)
                    acc[i][j] = __fmaf_rn(a4[i], x8[j], acc[i][j]);
        }
    };

    // shallow 1-ahead pipeline, unroll-2 for static buffer/slot names
    stageA(0, 0);
    uint4 kA = loadK(0), kB;
    vm0();
#pragma unroll 1
    for (int i = 0; i < NIT; i += 2) {
        stageA(1, i + 1); kB = loadK(i + 1);
        compute(0, kA, i);
        vm0();
        if (i + 2 < NIT) { stageA(0, i + 2); kA = loadK(i + 2); }
        compute(1, kB, i + 1);
        if (i + 2 < NIT) vm0();
    }

    // ---- epilogue: BN + LIF, exact reference op order (4 rows x 8 cols) ----
    if constexpr (MODE == 1) {
#pragma unroll
        for (int i = 0; i < 4; ++i) {
            const int o = o0 + to * 4 + i;
            const float bi = gp.proj_b[o], sc = gp.proj_bn_s[o], bc = gp.proj_bn_b[o];
            float* vr = gp.v_y + (size_t)o * NM + mb;
            const float* xr = gp.xT + ((size_t)gp.t * NC + o) * NM + mb;
            float* xyr = gp.xy + (size_t)o * NM + mb;
#pragma unroll
            for (int half = 0; half < 2; ++half) {
                const float4 vld = gp.t ? *(const float4*)(vr + half * 4) : make_float4(0, 0, 0, 0);
                const float4 xv4 = *(const float4*)(xr + half * 4);
                float vv[4] = {vld.x, vld.y, vld.z, vld.w};
                const float xvv[4] = {xv4.x, xv4.y, xv4.z, xv4.w};
                float xyo[4];
#pragma unroll
                for (int j = 0; j < 4; ++j) {
                    const float z = __fadd_rn(__fmul_rn(__fadd_rn(acc[i][half * 4 + j], bi), sc), bc);
                    int sp;
                    vv[j] = lif_step(z, vv[j], 1.0f, sp);
                    xyo[j] = __fadd_rn(xvv[j], (float)sp);   // residual x + y
                }
                *(float4*)(vr + half * 4) = make_float4(vv[0], vv[1], vv[2], vv[3]);
                *(float4*)(xyr + half * 4) = make_float4(xyo[0], xyo[1], xyo[2], xyo[3]);
            }
        }
    } else {  // MODE 3
        // 4-aligned halves never straddle a batch boundary (196 % 4 == 0)
        const int b0 = mb / NN,       n0 = mb - b0 * NN;
        const int b1 = (mb + 4) / NN, n1 = (mb + 4) - b1 * NN;
#pragma unroll
        for (int i = 0; i < 4; ++i) {
            const int o = o0 + to * 4 + i;
            const float bi = gp.mlp2_b[o], sc = gp.mlp2_bn_s[o], bc = gp.mlp2_bn_b[o];
            float* vr = gp.v_h2 + (size_t)o * NM + mb;
            const float* xyr = gp.xy + (size_t)o * NM + mb;
#pragma unroll
            for (int half = 0; half < 2; ++half) {
                const float4 vld = gp.t ? *(const float4*)(vr + half * 4) : make_float4(0, 0, 0, 0);
                const float4 xyv = *(const float4*)(xyr + half * 4);
                float vv[4] = {vld.x, vld.y, vld.z, vld.w};
                const float xyf[4] = {xyv.x, xyv.y, xyv.z, xyv.w};
                float ov[4];
#pragma unroll
                for (int j = 0; j < 4; ++j) {
                    const float z = __fadd_rn(__fmul_rn(__fadd_rn(acc[i][half * 4 + j], bi), sc), bc);
                    int sp;
                    vv[j] = lif_step(z, vv[j], 1.0f, sp);
                    ov[j] = __fadd_rn(xyf[j], (float)sp);
                }
                const int b = half ? b1 : b0;
                const int n = half ? n1 : n0;
                *(float4*)&gp.out[(((size_t)gp.t * NB + b) * NC + o) * NN + n] =
                    make_float4(ov[0], ov[1], ov[2], ov[3]);
                *(float4*)(vr + half * 4) = make_float4(vv[0], vv[1], vv[2], vv[3]);
            }
        }
    }
}

extern "C" void kernel_launch(void* const* d_in, const int* in_sizes, int n_in,
                              void* d_out, int out_size, void* d_ws, size_t ws_size,
                              hipStream_t stream) {
    const float* x       = (const float*)d_in[0];
    const float* q_w     = (const float*)d_in[1];
    const float* k_w     = (const float*)d_in[4];
    const float* proj_w  = (const float*)d_in[7];
    const float* mlp1_w  = (const float*)d_in[11];
    const float* mlp2_w  = (const float*)d_in[15];

    GP gp;
    gp.q_bn_s = (const float*)d_in[2];  gp.q_bn_b = (const float*)d_in[3];
    gp.k_bn_s = (const float*)d_in[5];  gp.k_bn_b = (const float*)d_in[6];
    gp.proj_b = (const float*)d_in[8];  gp.proj_bn_s = (const float*)d_in[9];  gp.proj_bn_b = (const float*)d_in[10];
    gp.mlp1_b = (const float*)d_in[12]; gp.mlp1_bn_s = (const float*)d_in[13]; gp.mlp1_bn_b = (const float*)d_in[14];
    gp.mlp2_b = (const float*)d_in[16]; gp.mlp2_bn_s = (const float*)d_in[17]; gp.mlp2_bn_b = (const float*)d_in[18];
    gp.out = (float*)d_out;

    char* ws = (char*)d_ws;
    size_t off = 0;
    auto alloc = [&](size_t bytes) -> void* {
        void* r = ws + off;
        off += (bytes + 255) & ~(size_t)255;
        return r;
    };
    float* wqkT   = (float*)alloc((size_t)512 * 1024 * 4);
    float* wprojT = (float*)alloc((size_t)512 * 512 * 4);
    float* wmlp1T = (float*)alloc((size_t)512 * 2048 * 4);
    float* wmlp2T = (float*)alloc((size_t)2048 * 512 * 4);
    float* xT     = (float*)alloc((size_t)NT * NC * NM * 4);
    gp.xy     = (float*)alloc((size_t)NC * NM * 4);
    gp.v_q    = (float*)alloc((size_t)NC * NM * 4);
    gp.v_k    = (float*)alloc((size_t)NC * NM * 4);
    gp.v_y    = (float*)alloc((size_t)NC * NM * 4);
    gp.v_h2   = (float*)alloc((size_t)NC * NM * 4);
    gp.v_h1   = (float*)alloc((size_t)NCH * NM * 4);
    gp.v_attn = (float*)alloc((size_t)NH * NM * 4);
    gp.q_bt   = (unsigned char*)alloc((size_t)NMB * NC);
    gp.k_bt   = (unsigned char*)alloc((size_t)NMB * NC);
    gp.h1_bt  = (unsigned char*)alloc((size_t)NMB * NCH);
    gp.attn_bt= (unsigned char*)alloc((size_t)NMB * NH);
    gp.wqkT = wqkT; gp.wprojT = wprojT; gp.wmlp1T = wmlp1T; gp.wmlp2T = wmlp2T;
    gp.xT = xT;

    // one-time (per call) layout transforms
    trw_k<<<dim3(16, 16), 256, 0, stream>>>(q_w,    wqkT,   512,  1024, 0);
    trw_k<<<dim3(16, 16), 256, 0, stream>>>(k_w,    wqkT,   512,  1024, 512);
    trw_k<<<dim3(16, 16), 256, 0, stream>>>(proj_w, wprojT, 512,  512,  0);
    trw_k<<<dim3(16, 64), 256, 0, stream>>>(mlp1_w, wmlp1T, 512,  2048, 0);
    trw_k<<<dim3(64, 16), 256, 0, stream>>>(mlp2_w, wmlp2T, 2048, 512,  0);
    permx_k<<<NT * NC * NB, 64, 0, stream>>>(x, xT);

    for (int t = 0; t < NT; ++t) {
        gp.t = t;
        gemm_unf<0><<<dim3(98, 32), 64, 0, stream>>>(gp);   // q,k -> bit-planes
        attn_k<<<dim3(4), 256, 0, stream>>>(gp);            // attn LIF -> bit-plane
        gemm_fus<1><<<dim3(98, 16), 64, 0, stream>>>(gp);   // proj -> v_y, xy
        gemm_unf<2><<<dim3(98, 64), 64, 0, stream>>>(gp);   // mlp1 -> h1 bit-plane
        gemm_fus<3><<<dim3(98, 16), 64, 0, stream>>>(gp);   // mlp2 -> out
    }
}

// Round 13
// 15493.185 us; speedup vs baseline: 1.0909x; 1.0007x over previous
//
#include <hip/hip_runtime.h>
#include <cstdint>

// ---- problem constants ----
#define NT  4
#define NB  32
#define NC  512
#define NCH 2048
#define NN  196
#define NM  (NB * NN)   // 6272 columns = 98*64
#define NMB (NM / 8)    // 784 column-bytes
#define NH  8

struct GP {
    const float *q_bn_s, *q_bn_b, *k_bn_s, *k_bn_b;
    const float *proj_b, *proj_bn_s, *proj_bn_b;
    const float *mlp1_b, *mlp1_bn_s, *mlp1_bn_b;
    const float *mlp2_b, *mlp2_bn_s, *mlp2_bn_b;
    const float *wqkT, *wprojT, *wmlp1T, *wmlp2T;  // [K][O] transposed weights
    const float *xT;                                // [T][C][M] permuted input
    float *xy;                                      // [C][M] x + y_spike (per t)
    float *v_q, *v_k, *v_y, *v_h1, *v_h2, *v_attn;  // LIF states
    // TRANSPOSED bit-planes: [col-byte][channel]  (bit j = column mB*8+j)
    unsigned char *q_bt, *k_bt, *h1_bt, *attn_bt;   // [NMB][512/512/2048/8]
    float *out;
    int t;
};

// Exact-f32 LIF step (bitwise-validated vs reference in R2-R12).
__device__ __forceinline__ float lif_step(float z, float v_old, float vth, int& sp) {
    float d = __fsub_rn(z, v_old);
    float h = __fmul_rn(d, 0.5f);
    float v = __fadd_rn(v_old, h);
    sp = (v >= vth) ? 1 : 0;
    return sp ? 0.0f : v;
}

typedef const void __attribute__((address_space(1))) gas_t;
typedef void __attribute__((address_space(3))) las_t;
__device__ __forceinline__ void gl_lds16(const float* g, float* l) {
    __builtin_amdgcn_global_load_lds((gas_t*)g, (las_t*)l, 16, 0, 0);
}
__device__ __forceinline__ void vm0() {
    asm volatile("s_waitcnt vmcnt(0)" ::: "memory");
}

// ---------------- pre-kernels ----------------

// dst[c*ldD + offD + o] = src[o*K + c]   (32x32 LDS tiles)
__global__ __launch_bounds__(256) void trw_k(const float* __restrict__ src,
                                             float* __restrict__ dst,
                                             int K, int ldD, int offD) {
    __shared__ float tle[32][33];
    const int c0 = blockIdx.x * 32, o0 = blockIdx.y * 32;
    const int tx = threadIdx.x & 31, ty = threadIdx.x >> 5;
#pragma unroll
    for (int r = 0; r < 4; ++r)
        tle[ty + r * 8][tx] = src[(size_t)(o0 + ty + r * 8) * K + c0 + tx];
    __syncthreads();
#pragma unroll
    for (int r = 0; r < 4; ++r)
        dst[(size_t)(c0 + ty + r * 8) * ldD + offD + o0 + tx] = tle[tx][ty + r * 8];
}

// xT[t][c][b][n] = x[t][b][c][n]
__global__ __launch_bounds__(64) void permx_k(const float* __restrict__ x,
                                              float* __restrict__ xT) {
    const int id = blockIdx.x;         // t*16384 + c*32 + b
    const int b = id & 31;
    const int c = (id >> 5) & 511;
    const int t = id >> 14;
    const float* s = x + ((size_t)(t * NB + b) * NC + c) * NN;
    float* d = xT + ((size_t)(t * NC + c) * NB + b) * NN;
    for (int n = threadIdx.x; n < NN; n += 64) d[n] = s[n];
}

// attn LIF: thread = col-byte mB, all 8 heads; SWAR popcount over qT row.
__global__ __launch_bounds__(256) void attn_k(GP gp) {
    const int mB = blockIdx.x * 256 + threadIdx.x;
    if (mB >= NMB) return;
    const unsigned* qr = (const unsigned*)(gp.q_bt + (size_t)mB * NC);  // 128 dwords
    unsigned outB[8];
#pragma unroll
    for (int h = 0; h < NH; ++h) {
        unsigned a[8];
#pragma unroll
        for (int j = 0; j < 8; ++j) a[j] = 0;
#pragma unroll
        for (int d = 0; d < 16; ++d) {
            const unsigned w = qr[h * 16 + d];
#pragma unroll
            for (int j = 0; j < 8; ++j) a[j] += (w >> j) & 0x01010101u;
        }
        float* vr = gp.v_attn + (size_t)h * NM + mB * 8;
        unsigned ob = 0;
#pragma unroll
        for (int j = 0; j < 8; ++j) {
            unsigned s = a[j] + (a[j] >> 16);
            s = (s + (s >> 8)) & 0xff;                   // sum of 64 bits
            float v = gp.t ? vr[j] : 0.0f;
            int sp;
            v = lif_step((float)s, v, 0.5f, sp);          // dyadic-exact
            vr[j] = v;
            ob |= (unsigned)sp << j;
        }
        outB[h] = ob;
    }
    uint2 w;
    w.x = outB[0] | (outB[1] << 8) | (outB[2] << 16) | (outB[3] << 24);
    w.y = outB[4] | (outB[5] << 8) | (outB[6] << 16) | (outB[7] << 24);
    *(uint2*)(gp.attn_bt + (size_t)mB * 8) = w;
}

// ---------------- unfused GEMM + BN + LIF (MODE 0 = q&k, MODE 2 = mlp1) ----------------
// R8-proven: 1 wave/block, 2-buffer wave-private LDS, no barriers, vm0 sync.
template <int MODE>
__global__ __launch_bounds__(64) void gemm_unf(GP gp) {
    constexpr int LDA = (MODE == 0) ? 1024 : 2048;
    constexpr int BK = 16;
    constexpr int NIT = 512 / BK;             // 32

    __shared__ float As[2][BK][32];
    __shared__ float Xs[2][BK][64];

    const int lane = threadIdx.x;
    const int to = lane & 7;
    const int tn = lane >> 3;
    const int m0 = blockIdx.x * 64;
    const int ot = blockIdx.y;
    const int o0 = ot * 32;
    const int mb = m0 + tn * 8;
    const int mbB = (m0 >> 3) + tn;

    const float* wA = (MODE == 0) ? gp.wqkT : gp.wmlp1T;
    const float* xf = (MODE == 0) ? gp.xT + (size_t)gp.t * NC * NM : gp.xy;

    auto stageA = [&](int buf, int s) {
#pragma unroll
        for (int r = 0; r < 2; ++r)
            gl_lds16(wA + (size_t)(s * BK + r * 8 + (lane >> 3)) * LDA + o0 + (lane & 7) * 4,
                     &As[buf][r * 8][0]);
    };
    auto stageX = [&](int buf, int s) {
#pragma unroll
        for (int r = 0; r < 4; ++r)
            gl_lds16(xf + (size_t)(s * BK + r * 4 + (lane >> 4)) * NM + m0 + (lane & 15) * 4,
                     &Xs[buf][r * 4][0]);
    };

    float acc[4][8];
#pragma unroll
    for (int i = 0; i < 4; ++i)
#pragma unroll
        for (int j = 0; j < 8; ++j) acc[i][j] = 0.0f;

    auto compute = [&](int cur) {
#pragma unroll 4
        for (int kk = 0; kk < BK; ++kk) {
            const float4 av = *(const float4*)&As[cur][kk][to * 4];
            const float4 x0 = *(const float4*)&Xs[cur][kk][tn * 8];
            const float4 x1 = *(const float4*)&Xs[cur][kk][tn * 8 + 4];
            const float a4[4] = {av.x, av.y, av.z, av.w};
            const float x8[8] = {x0.x, x0.y, x0.z, x0.w, x1.x, x1.y, x1.z, x1.w};
#pragma unroll
            for (int i = 0; i < 4; ++i)
#pragma unroll
                for (int j = 0; j < 8; ++j)
                    acc[i][j] = __fadd_rn(acc[i][j], __fmul_rn(a4[i], x8[j]));
        }
    };

    stageA(0, 0); stageX(0, 0);
    vm0();
#pragma unroll 1
    for (int it = 0; it < NIT; ++it) {
        const int cur = it & 1;
        const bool more = (it + 1 < NIT);
        if (more) { stageA(cur ^ 1, it + 1); stageX(cur ^ 1, it + 1); }
        compute(cur);
        if (more) vm0();
    }

    // epilogue: BN + LIF; bits go to TRANSPOSED planes (u32 = 4 consecutive o)
    if constexpr (MODE == 0) {
        const bool isq = (ot < 16);
        const float* bs = isq ? gp.q_bn_s : gp.k_bn_s;
        const float* bbv = isq ? gp.q_bn_b : gp.k_bn_b;
        float* vb = isq ? gp.v_q : gp.v_k;
        unsigned char* sb = isq ? gp.q_bt : gp.k_bt;
        const int ob = (ot & 15) * 32;
        unsigned pw = 0;
#pragma unroll
        for (int i = 0; i < 4; ++i) {
            const int oo = ob + to * 4 + i;
            const float sc = bs[oo], bc = bbv[oo];
            float* vr = vb + (size_t)oo * NM + mb;
            float vv[8];
            if (gp.t) {
                const float4 v0 = *(const float4*)vr, v1 = *(const float4*)(vr + 4);
                vv[0] = v0.x; vv[1] = v0.y; vv[2] = v0.z; vv[3] = v0.w;
                vv[4] = v1.x; vv[5] = v1.y; vv[6] = v1.z; vv[7] = v1.w;
            } else {
#pragma unroll
                for (int j = 0; j < 8; ++j) vv[j] = 0.0f;
            }
            unsigned pb = 0;
#pragma unroll
            for (int j = 0; j < 8; ++j) {
                const float z = __fadd_rn(__fmul_rn(acc[i][j], sc), bc);
                int sp;
                vv[j] = lif_step(z, vv[j], 1.0f, sp);
                pb |= (unsigned)sp << j;
            }
            *(float4*)vr = make_float4(vv[0], vv[1], vv[2], vv[3]);
            *(float4*)(vr + 4) = make_float4(vv[4], vv[5], vv[6], vv[7]);
            pw |= pb << (i * 8);
        }
        *(unsigned*)(sb + (size_t)mbB * NC + ob + to * 4) = pw;
    } else {
        const int ob = ot * 32;
        unsigned pw = 0;
#pragma unroll
        for (int i = 0; i < 4; ++i) {
            const int o = ob + to * 4 + i;
            const float bi = gp.mlp1_b[o], sc = gp.mlp1_bn_s[o], bc = gp.mlp1_bn_b[o];
            float* vr = gp.v_h1 + (size_t)o * NM + mb;
            float vv[8];
            if (gp.t) {
                const float4 v0 = *(const float4*)vr, v1 = *(const float4*)(vr + 4);
                vv[0] = v0.x; vv[1] = v0.y; vv[2] = v0.z; vv[3] = v0.w;
                vv[4] = v1.x; vv[5] = v1.y; vv[6] = v1.z; vv[7] = v1.w;
            } else {
#pragma unroll
                for (int j = 0; j < 8; ++j) vv[j] = 0.0f;
            }
            unsigned pb = 0;
#pragma unroll
            for (int j = 0; j < 8; ++j) {
                const float z = __fadd_rn(__fmul_rn(__fadd_rn(acc[i][j], bi), sc), bc);
                int sp;
                vv[j] = lif_step(z, vv[j], 1.0f, sp);
                pb |= (unsigned)sp << j;
            }
            *(float4*)vr = make_float4(vv[0], vv[1], vv[2], vv[3]);
            *(float4*)(vr + 4) = make_float4(vv[4], vv[5], vv[6], vv[7]);
            pw |= pb << (i * 8);
        }
        *(unsigned*)(gp.h1_bt + (size_t)mbB * NCH + ob + to * 4) = pw;
    }
}

// ---------------- fused GEMM + BN + LIF (MODE 1 = proj, MODE 3 = mlp2) ----------------
// A in LDS (2-buffer, 0.5 B/FMA), X = bit-plane in REGISTERS.
// R11/R12 post-mortem: with only 4KB LDS, hipcc's default occupancy
// heuristic capped VGPR at 44 (< the ~52 live regs needed) -> acc spilled
// to scratch -> 6% VALUBusy, invariant to pipeline depth. The fix is
// __launch_bounds__(64, 1): declare min 1 wave/EU so the allocator may
// use the registers the kernel actually needs. (R5's failure was the
// OPPOSITE: forcing waves/EU too HIGH.)
template <int MODE>
__global__ __launch_bounds__(64, 1) void gemm_fus(GP gp) {
    constexpr int K_TOT = (MODE == 3) ? 2048 : 512;
    constexpr int BK = 16;
    constexpr int NIT = K_TOT / BK;           // 32 or 128 (even)

    __shared__ float As[2][BK][32];           // 4 KB

    const int lane = threadIdx.x;
    const int to = lane & 7;                  // 4 rows each
    const int tn = lane >> 3;                 // 8 cols each
    const int m0 = blockIdx.x * 64;
    const int o0 = blockIdx.y * 32;
    const int mb = m0 + tn * 8;
    const int mB = (m0 >> 3) + tn;

    const float* wA = (MODE == 1) ? gp.wprojT : gp.wmlp2T;
    const unsigned char* xbt = (MODE == 1) ? gp.k_bt : gp.h1_bt;

    uint2 aU2 = {0, 0};
    if constexpr (MODE == 1)
        aU2 = *(const uint2*)(gp.attn_bt + (size_t)mB * 8);

    auto stageA = [&](int buf, int s) {
#pragma unroll
        for (int r = 0; r < 2; ++r)
            gl_lds16(wA + (size_t)(s * BK + r * 8 + (lane >> 3)) * 512 + o0 + (lane & 7) * 4,
                     &As[buf][r * 8][0]);
    };
    auto loadK = [&](int s) -> uint4 {
        return *(const uint4*)(xbt + (size_t)mB * K_TOT + s * BK);
    };

    float acc[4][8];
#pragma unroll
    for (int i = 0; i < 4; ++i)
#pragma unroll
        for (int j = 0; j < 8; ++j) acc[i][j] = 0.0f;

    auto compute = [&](int cb, uint4 kb, int it) {
        unsigned dw[4] = {kb.x, kb.y, kb.z, kb.w};
        if constexpr (MODE == 1) {
            const int h = it >> 2;            // 64 c per head, 16 c per iter
            const unsigned ab = ((h < 4) ? (aU2.x >> (h * 8)) : (aU2.y >> ((h - 4) * 8))) & 0xffu;
            const unsigned ar = ab * 0x01010101u;
#pragma unroll
            for (int q = 0; q < 4; ++q) dw[q] &= ar;   // x_one = k & attn (exact)
        }
#pragma unroll
        for (int kk = 0; kk < BK; ++kk) {
            const float4 av = *(const float4*)&As[cb][kk][to * 4];
            const float a4[4] = {av.x, av.y, av.z, av.w};
            const unsigned bsel = dw[kk >> 2] >> ((kk & 3) * 8);
            float x8[8];
#pragma unroll
            for (int j = 0; j < 8; ++j) x8[j] = (float)((bsel >> j) & 1u);
#pragma unroll
            for (int i = 0; i < 4; ++i)
#pragma unroll
                for (int j = 0; j < 8; ++j)
                    acc[i][j] = __fmaf_rn(a4[i], x8[j], acc[i][j]);
        }
    };

    // shallow 1-ahead pipeline, unroll-2 for static buffer/slot names
    stageA(0, 0);
    uint4 kA = loadK(0), kB;
    vm0();
#pragma unroll 1
    for (int i = 0; i < NIT; i += 2) {
        stageA(1, i + 1); kB = loadK(i + 1);
        compute(0, kA, i);
        vm0();
        if (i + 2 < NIT) { stageA(0, i + 2); kA = loadK(i + 2); }
        compute(1, kB, i + 1);
        if (i + 2 < NIT) vm0();
    }

    // ---- epilogue: BN + LIF, exact reference op order (4 rows x 8 cols) ----
    if constexpr (MODE == 1) {
#pragma unroll
        for (int i = 0; i < 4; ++i) {
            const int o = o0 + to * 4 + i;
            const float bi = gp.proj_b[o], sc = gp.proj_bn_s[o], bc = gp.proj_bn_b[o];
            float* vr = gp.v_y + (size_t)o * NM + mb;
            const float* xr = gp.xT + ((size_t)gp.t * NC + o) * NM + mb;
            float* xyr = gp.xy + (size_t)o * NM + mb;
#pragma unroll
            for (int half = 0; half < 2; ++half) {
                const float4 vld = gp.t ? *(const float4*)(vr + half * 4) : make_float4(0, 0, 0, 0);
                const float4 xv4 = *(const float4*)(xr + half * 4);
                float vv[4] = {vld.x, vld.y, vld.z, vld.w};
                const float xvv[4] = {xv4.x, xv4.y, xv4.z, xv4.w};
                float xyo[4];
#pragma unroll
                for (int j = 0; j < 4; ++j) {
                    const float z = __fadd_rn(__fmul_rn(__fadd_rn(acc[i][half * 4 + j], bi), sc), bc);
                    int sp;
                    vv[j] = lif_step(z, vv[j], 1.0f, sp);
                    xyo[j] = __fadd_rn(xvv[j], (float)sp);   // residual x + y
                }
                *(float4*)(vr + half * 4) = make_float4(vv[0], vv[1], vv[2], vv[3]);
                *(float4*)(xyr + half * 4) = make_float4(xyo[0], xyo[1], xyo[2], xyo[3]);
            }
        }
    } else {  // MODE 3
        // 4-aligned halves never straddle a batch boundary (196 % 4 == 0)
        const int b0 = mb / NN,       n0 = mb - b0 * NN;
        const int b1 = (mb + 4) / NN, n1 = (mb + 4) - b1 * NN;
#pragma unroll
        for (int i = 0; i < 4; ++i) {
            const int o = o0 + to * 4 + i;
            const float bi = gp.mlp2_b[o], sc = gp.mlp2_bn_s[o], bc = gp.mlp2_bn_b[o];
            float* vr = gp.v_h2 + (size_t)o * NM + mb;
            const float* xyr = gp.xy + (size_t)o * NM + mb;
#pragma unroll
            for (int half = 0; half < 2; ++half) {
                const float4 vld = gp.t ? *(const float4*)(vr + half * 4) : make_float4(0, 0, 0, 0);
                const float4 xyv = *(const float4*)(xyr + half * 4);
                float vv[4] = {vld.x, vld.y, vld.z, vld.w};
                const float xyf[4] = {xyv.x, xyv.y, xyv.z, xyv.w};
                float ov[4];
#pragma unroll
                for (int j = 0; j < 4; ++j) {
                    const float z = __fadd_rn(__fmul_rn(__fadd_rn(acc[i][half * 4 + j], bi), sc), bc);
                    int sp;
                    vv[j] = lif_step(z, vv[j], 1.0f, sp);
                    ov[j] = __fadd_rn(xyf[j], (float)sp);
                }
                const int b = half ? b1 : b0;
                const int n = half ? n1 : n0;
                *(float4*)&gp.out[(((size_t)gp.t * NB + b) * NC + o) * NN + n] =
                    make_float4(ov[0], ov[1], ov[2], ov[3]);
                *(float4*)(vr + half * 4) = make_float4(vv[0], vv[1], vv[2], vv[3]);
            }
        }
    }
}

extern "C" void kernel_launch(void* const* d_in, const int* in_sizes, int n_in,
                              void* d_out, int out_size, void* d_ws, size_t ws_size,
                              hipStream_t stream) {
    const float* x       = (const float*)d_in[0];
    const float* q_w     = (const float*)d_in[1];
    const float* k_w     = (const float*)d_in[4];
    const float* proj_w  = (const float*)d_in[7];
    const float* mlp1_w  = (const float*)d_in[11];
    const float* mlp2_w  = (const float*)d_in[15];

    GP gp;
    gp.q_bn_s = (const float*)d_in[2];  gp.q_bn_b = (const float*)d_in[3];
    gp.k_bn_s = (const float*)d_in[5];  gp.k_bn_b = (const float*)d_in[6];
    gp.proj_b = (const float*)d_in[8];  gp.proj_bn_s = (const float*)d_in[9];  gp.proj_bn_b = (const float*)d_in[10];
    gp.mlp1_b = (const float*)d_in[12]; gp.mlp1_bn_s = (const float*)d_in[13]; gp.mlp1_bn_b = (const float*)d_in[14];
    gp.mlp2_b = (const float*)d_in[16]; gp.mlp2_bn_s = (const float*)d_in[17]; gp.mlp2_bn_b = (const float*)d_in[18];
    gp.out = (float*)d_out;

    char* ws = (char*)d_ws;
    size_t off = 0;
    auto alloc = [&](size_t bytes) -> void* {
        void* r = ws + off;
        off += (bytes + 255) & ~(size_t)255;
        return r;
    };
    float* wqkT   = (float*)alloc((size_t)512 * 1024 * 4);
    float* wprojT = (float*)alloc((size_t)512 * 512 * 4);
    float* wmlp1T = (float*)alloc((size_t)512 * 2048 * 4);
    float* wmlp2T = (float*)alloc((size_t)2048 * 512 * 4);
    float* xT     = (float*)alloc((size_t)NT * NC * NM * 4);
    gp.xy     = (float*)alloc((size_t)NC * NM * 4);
    gp.v_q    = (float*)alloc((size_t)NC * NM * 4);
    gp.v_k    = (float*)alloc((size_t)NC * NM * 4);
    gp.v_y    = (float*)alloc((size_t)NC * NM * 4);
    gp.v_h2   = (float*)alloc((size_t)NC * NM * 4);
    gp.v_h1   = (float*)alloc((size_t)NCH * NM * 4);
    gp.v_attn = (float*)alloc((size_t)NH * NM * 4);
    gp.q_bt   = (unsigned char*)alloc((size_t)NMB * NC);
    gp.k_bt   = (unsigned char*)alloc((size_t)NMB * NC);
    gp.h1_bt  = (unsigned char*)alloc((size_t)NMB * NCH);
    gp.attn_bt= (unsigned char*)alloc((size_t)NMB * NH);
    gp.wqkT = wqkT; gp.wprojT = wprojT; gp.wmlp1T = wmlp1T; gp.wmlp2T = wmlp2T;
    gp.xT = xT;

    // one-time (per call) layout transforms
    trw_k<<<dim3(16, 16), 256, 0, stream>>>(q_w,    wqkT,   512,  1024, 0);
    trw_k<<<dim3(16, 16), 256, 0, stream>>>(k_w,    wqkT,   512,  1024, 512);
    trw_k<<<dim3(16, 16), 256, 0, stream>>>(proj_w, wprojT, 512,  512,  0);
    trw_k<<<dim3(16, 64), 256, 0, stream>>>(mlp1_w, wmlp1T, 512,  2048, 0);
    trw_k<<<dim3(64, 16), 256, 0, stream>>>(mlp2_w, wmlp2T, 2048, 512,  0);
    permx_k<<<NT * NC * NB, 64, 0, stream>>>(x, xT);

    for (int t = 0; t < NT; ++t) {
        gp.t = t;
        gemm_unf<0><<<dim3(98, 32), 64, 0, stream>>>(gp);   // q,k -> bit-planes
        attn_k<<<dim3(4), 256, 0, stream>>>(gp);            // attn LIF -> bit-plane
        gemm_fus<1><<<dim3(98, 16), 64, 0, stream>>>(gp);   // proj -> v_y, xy
        gemm_unf<2><<<dim3(98, 64), 64, 0, stream>>>(gp);   // mlp1 -> h1 bit-plane
        gemm_fus<3><<<dim3(98, 16), 64, 0, stream>>>(gp);   // mlp2 -> out
    }
}

// Round 14
// 2733.074 us; speedup vs baseline: 6.1838x; 5.6688x over previous
//
#include <hip/hip_runtime.h>
#include <cstdint>

// ---- problem constants ----
#define NT  4
#define NB  32
#define NC  512
#define NCH 2048
#define NN  196
#define NM  (NB * NN)   // 6272 columns = 98*64
#define NMB (NM / 8)    // 784 column-bytes
#define NH  8

struct GP {
    const float *q_bn_s, *q_bn_b, *k_bn_s, *k_bn_b;
    const float *proj_b, *proj_bn_s, *proj_bn_b;
    const float *mlp1_b, *mlp1_bn_s, *mlp1_bn_b;
    const float *mlp2_b, *mlp2_bn_s, *mlp2_bn_b;
    const float *wqkT, *wprojT, *wmlp1T, *wmlp2T;  // [K][O] transposed weights
    const float *xT;                                // [T][C][M] permuted input
    float *xy;                                      // [C][M] x + y_spike (per t)
    float *v_q, *v_k, *v_y, *v_h1, *v_h2, *v_attn;  // LIF states
    // bit-planes [C][NMB]: byte mB holds columns mB*8..mB*8+7 of channel c
    unsigned char *q_bt, *k_bt, *h1_bt, *attn_bt;   // [512/512/2048/8][NMB]
    float *out;
    int t;
};

// Exact-f32 LIF step (bitwise-validated vs reference in R2-R13).
__device__ __forceinline__ float lif_step(float z, float v_old, float vth, int& sp) {
    float d = __fsub_rn(z, v_old);
    float h = __fmul_rn(d, 0.5f);
    float v = __fadd_rn(v_old, h);
    sp = (v >= vth) ? 1 : 0;
    return sp ? 0.0f : v;
}

typedef const void __attribute__((address_space(1))) gas_t;
typedef void __attribute__((address_space(3))) las_t;
__device__ __forceinline__ void gl_lds16(const float* g, float* l) {
    __builtin_amdgcn_global_load_lds((gas_t*)g, (las_t*)l, 16, 0, 0);
}
__device__ __forceinline__ void vm0() {
    asm volatile("s_waitcnt vmcnt(0)" ::: "memory");
}
__device__ __forceinline__ void lgkm0() {
    asm volatile("s_waitcnt lgkmcnt(0)" ::: "memory");
}

// ---------------- pre-kernels ----------------

// dst[c*ldD + offD + o] = src[o*K + c]   (32x32 LDS tiles)
__global__ __launch_bounds__(256) void trw_k(const float* __restrict__ src,
                                             float* __restrict__ dst,
                                             int K, int ldD, int offD) {
    __shared__ float tle[32][33];
    const int c0 = blockIdx.x * 32, o0 = blockIdx.y * 32;
    const int tx = threadIdx.x & 31, ty = threadIdx.x >> 5;
#pragma unroll
    for (int r = 0; r < 4; ++r)
        tle[ty + r * 8][tx] = src[(size_t)(o0 + ty + r * 8) * K + c0 + tx];
    __syncthreads();
#pragma unroll
    for (int r = 0; r < 4; ++r)
        dst[(size_t)(c0 + ty + r * 8) * ldD + offD + o0 + tx] = tle[tx][ty + r * 8];
}

// xT[t][c][b][n] = x[t][b][c][n]
__global__ __launch_bounds__(64) void permx_k(const float* __restrict__ x,
                                              float* __restrict__ xT) {
    const int id = blockIdx.x;         // t*16384 + c*32 + b
    const int b = id & 31;
    const int c = (id >> 5) & 511;
    const int t = id >> 14;
    const float* s = x + ((size_t)(t * NB + b) * NC + c) * NN;
    float* d = xT + ((size_t)(t * NC + c) * NB + b) * NN;
    for (int n = threadIdx.x; n < NN; n += 64) d[n] = s[n];
}

// attn LIF on bit-packed q spikes: thread = (h, column-byte), handles 8 cols.
__global__ __launch_bounds__(256) void attn_k(GP gp) {
    const int id = blockIdx.x * 256 + threadIdx.x;
    if (id >= NH * NMB) return;        // 8*784 = 6272
    const int mB = id % NMB;
    const int h = id / NMB;
    int s[8];
#pragma unroll
    for (int j = 0; j < 8; ++j) s[j] = 0;
    const unsigned char* q = gp.q_bt + (size_t)(h * 64) * NMB + mB;
#pragma unroll 8
    for (int d = 0; d < 64; ++d) {
        const unsigned b = q[(size_t)d * NMB];
#pragma unroll
        for (int j = 0; j < 8; ++j) s[j] += (b >> j) & 1;
    }
    unsigned ob = 0;
#pragma unroll
    for (int j = 0; j < 8; ++j) {
        const int m = mB * 8 + j;
        float v = gp.t ? gp.v_attn[(size_t)h * NM + m] : 0.0f;
        int sp;
        v = lif_step((float)s[j], v, 0.5f, sp);   // dyadic-exact
        gp.v_attn[(size_t)h * NM + m] = v;
        ob |= (unsigned)sp << j;
    }
    gp.attn_bt[(size_t)h * NMB + mB] = (unsigned char)ob;
}

// ---------------- unfused GEMM + BN + LIF (MODE 0 = q&k, MODE 2 = mlp1) ----------------
// R8/R10-proven: 1 wave/block, 2-buffer wave-private LDS, no barriers, vm0 sync.
template <int MODE>
__global__ __launch_bounds__(64) void gemm_unf(GP gp) {
    constexpr int LDA = (MODE == 0) ? 1024 : 2048;
    constexpr int BK = 16;
    constexpr int NIT = 512 / BK;             // 32

    __shared__ float As[2][BK][32];           // 4 KB
    __shared__ float Xs[2][BK][64];           // 8 KB

    const int lane = threadIdx.x;
    const int to = lane & 7;
    const int tn = lane >> 3;
    const int m0 = blockIdx.x * 64;
    const int ot = blockIdx.y;
    const int o0 = ot * 32;
    const int mb = m0 + tn * 8;
    const int mbB = (m0 >> 3) + tn;

    const float* wA = (MODE == 0) ? gp.wqkT : gp.wmlp1T;
    const float* xf = (MODE == 0) ? gp.xT + (size_t)gp.t * NC * NM : gp.xy;

    auto stageA = [&](int buf, int s) {
#pragma unroll
        for (int r = 0; r < 2; ++r)
            gl_lds16(wA + (size_t)(s * BK + r * 8 + (lane >> 3)) * LDA + o0 + (lane & 7) * 4,
                     &As[buf][r * 8][0]);
    };
    auto stageX = [&](int buf, int s) {
#pragma unroll
        for (int r = 0; r < 4; ++r)
            gl_lds16(xf + (size_t)(s * BK + r * 4 + (lane >> 4)) * NM + m0 + (lane & 15) * 4,
                     &Xs[buf][r * 4][0]);
    };

    float acc[4][8];
#pragma unroll
    for (int i = 0; i < 4; ++i)
#pragma unroll
        for (int j = 0; j < 8; ++j) acc[i][j] = 0.0f;

    auto compute = [&](int cur) {
#pragma unroll 4
        for (int kk = 0; kk < BK; ++kk) {
            const float4 av = *(const float4*)&As[cur][kk][to * 4];
            const float4 x0 = *(const float4*)&Xs[cur][kk][tn * 8];
            const float4 x1 = *(const float4*)&Xs[cur][kk][tn * 8 + 4];
            const float a4[4] = {av.x, av.y, av.z, av.w};
            const float x8[8] = {x0.x, x0.y, x0.z, x0.w, x1.x, x1.y, x1.z, x1.w};
#pragma unroll
            for (int i = 0; i < 4; ++i)
#pragma unroll
                for (int j = 0; j < 8; ++j)
                    acc[i][j] = __fadd_rn(acc[i][j], __fmul_rn(a4[i], x8[j]));
        }
    };

    stageA(0, 0); stageX(0, 0);
    vm0();
#pragma unroll 1
    for (int it = 0; it < NIT; ++it) {
        const int cur = it & 1;
        const bool more = (it + 1 < NIT);
        if (more) { stageA(cur ^ 1, it + 1); stageX(cur ^ 1, it + 1); }
        compute(cur);
        if (more) vm0();
    }

    // epilogue: BN + LIF; spike bits -> [C][NMB] planes (1 byte per row)
    if constexpr (MODE == 0) {
        const bool isq = (ot < 16);
        const float* bs = isq ? gp.q_bn_s : gp.k_bn_s;
        const float* bbv = isq ? gp.q_bn_b : gp.k_bn_b;
        float* vb = isq ? gp.v_q : gp.v_k;
        unsigned char* sb = isq ? gp.q_bt : gp.k_bt;
        const int ob = (ot & 15) * 32;
#pragma unroll
        for (int i = 0; i < 4; ++i) {
            const int oo = ob + to * 4 + i;
            const float sc = bs[oo], bc = bbv[oo];
            float* vr = vb + (size_t)oo * NM + mb;
            float vv[8];
            if (gp.t) {
                const float4 v0 = *(const float4*)vr, v1 = *(const float4*)(vr + 4);
                vv[0] = v0.x; vv[1] = v0.y; vv[2] = v0.z; vv[3] = v0.w;
                vv[4] = v1.x; vv[5] = v1.y; vv[6] = v1.z; vv[7] = v1.w;
            } else {
#pragma unroll
                for (int j = 0; j < 8; ++j) vv[j] = 0.0f;
            }
            unsigned pb = 0;
#pragma unroll
            for (int j = 0; j < 8; ++j) {
                const float z = __fadd_rn(__fmul_rn(acc[i][j], sc), bc);
                int sp;
                vv[j] = lif_step(z, vv[j], 1.0f, sp);
                pb |= (unsigned)sp << j;
            }
            *(float4*)vr = make_float4(vv[0], vv[1], vv[2], vv[3]);
            *(float4*)(vr + 4) = make_float4(vv[4], vv[5], vv[6], vv[7]);
            sb[(size_t)oo * NMB + mbB] = (unsigned char)pb;
        }
    } else {
        const int ob = ot * 32;
#pragma unroll
        for (int i = 0; i < 4; ++i) {
            const int o = ob + to * 4 + i;
            const float bi = gp.mlp1_b[o], sc = gp.mlp1_bn_s[o], bc = gp.mlp1_bn_b[o];
            float* vr = gp.v_h1 + (size_t)o * NM + mb;
            float vv[8];
            if (gp.t) {
                const float4 v0 = *(const float4*)vr, v1 = *(const float4*)(vr + 4);
                vv[0] = v0.x; vv[1] = v0.y; vv[2] = v0.z; vv[3] = v0.w;
                vv[4] = v1.x; vv[5] = v1.y; vv[6] = v1.z; vv[7] = v1.w;
            } else {
#pragma unroll
                for (int j = 0; j < 8; ++j) vv[j] = 0.0f;
            }
            unsigned pb = 0;
#pragma unroll
            for (int j = 0; j < 8; ++j) {
                const float z = __fadd_rn(__fmul_rn(__fadd_rn(acc[i][j], bi), sc), bc);
                int sp;
                vv[j] = lif_step(z, vv[j], 1.0f, sp);
                pb |= (unsigned)sp << j;
            }
            *(float4*)vr = make_float4(vv[0], vv[1], vv[2], vv[3]);
            *(float4*)(vr + 4) = make_float4(vv[4], vv[5], vv[6], vv[7]);
            gp.h1_bt[(size_t)o * NMB + mbB] = (unsigned char)pb;
        }
    }
}

// ---------------- fused GEMM + BN + LIF (MODE 1 = proj, MODE 3 = mlp2) ----------------
// 32o x 64m tile, per-thread 4x8 (1.5 B LDS per FMA -> cap 67% vs the 4x4
// geometry's 2.0 B/FMA -> 50% cap, which R9/R10 measured exactly 47-50%).
// X bits are staged ushort->LDS floats (flushB): R7/R11-R13 proved hipcc
// demotes register-resident global prefetch (44 VGPR / 6% VALU in all four
// attempts); LDS-staged X is the only prefetch idiom it preserves.
// R8's proven 2-buffer / vm0 ordering. No barriers (wave-private LDS).
template <int MODE>
__global__ __launch_bounds__(64) void gemm_fus(GP gp) {
    constexpr int K_TOT = (MODE == 3) ? 2048 : 512;
    constexpr int BK = 16;
    constexpr int NIT = K_TOT / BK;           // 32 or 128 (even)

    __shared__ float As[2][BK][32];           // 4 KB
    __shared__ float Xs[2][BK][68];           // 8.5 KB (pad 64->68 floats)

    const int lane = threadIdx.x;
    const int to = lane & 7;                  // 4 rows each
    const int tn = lane >> 3;                 // 8 cols each
    const int m0 = blockIdx.x * 64;
    const int o0 = blockIdx.y * 32;
    const int mb = m0 + tn * 8;
    const int mB0 = m0 >> 3;

    const float* wA = (MODE == 1) ? gp.wprojT : gp.wmlp2T;
    const unsigned char* xbt = (MODE == 1) ? gp.k_bt : gp.h1_bt;

    const int xr = lane >> 2;                 // staging row 0..15
    const int xp = lane & 3;                  // col-byte pair 0..3 (16 cols)

    auto stageA = [&](int buf, int s) {
#pragma unroll
        for (int r = 0; r < 2; ++r)
            gl_lds16(wA + (size_t)(s * BK + r * 8 + (lane >> 3)) * 512 + o0 + (lane & 7) * 4,
                     &As[buf][r * 8][0]);
    };
    // load 16 columns' bits for row xr: ushort k (and attn ushort for MODE 1)
    auto loadB = [&](int s) -> unsigned {
        const int c = s * BK + xr;
        unsigned w = *(const unsigned short*)(xbt + (size_t)c * NMB + mB0 + xp * 2);
        if constexpr (MODE == 1) {
            const unsigned a = *(const unsigned short*)(gp.attn_bt + (size_t)(c >> 6) * NMB + mB0 + xp * 2);
            w |= a << 16;
        }
        return w;
    };
    auto flushB = [&](int buf, unsigned wv) {
        const unsigned w = (MODE == 1) ? ((wv & 0xffffu) & (wv >> 16)) : wv;  // AND == product (exact)
        float* d = &Xs[buf][xr][xp * 16];
#pragma unroll
        for (int q = 0; q < 4; ++q) {
            float4 f;
            f.x = (float)((w >> (q * 4 + 0)) & 1u);
            f.y = (float)((w >> (q * 4 + 1)) & 1u);
            f.z = (float)((w >> (q * 4 + 2)) & 1u);
            f.w = (float)((w >> (q * 4 + 3)) & 1u);
            *(float4*)(d + q * 4) = f;
        }
    };

    float acc[4][8];
#pragma unroll
    for (int i = 0; i < 4; ++i)
#pragma unroll
        for (int j = 0; j < 8; ++j) acc[i][j] = 0.0f;

    auto compute = [&](int cb) {
#pragma unroll 4
        for (int kk = 0; kk < BK; ++kk) {
            const float4 av = *(const float4*)&As[cb][kk][to * 4];
            const float4 x0 = *(const float4*)&Xs[cb][kk][tn * 8];
            const float4 x1 = *(const float4*)&Xs[cb][kk][tn * 8 + 4];
            const float a4[4] = {av.x, av.y, av.z, av.w};
            const float x8[8] = {x0.x, x0.y, x0.z, x0.w, x1.x, x1.y, x1.z, x1.w};
#pragma unroll
            for (int i = 0; i < 4; ++i)
#pragma unroll
                for (int j = 0; j < 8; ++j)
                    acc[i][j] = __fmaf_rn(a4[i], x8[j], acc[i][j]);
        }
    };

    // prologue
    stageA(0, 0);
    unsigned w0 = loadB(0);
    vm0();
    flushB(0, w0);
    lgkm0();

    // main loop: R8 ordering, unroll-2 for static buffer names
#pragma unroll 1
    for (int i = 0; i < NIT; i += 2) {
        stageA(1, i + 1);
        unsigned w1 = loadB(i + 1);
        compute(0);
        vm0();
        flushB(1, w1);
        lgkm0();
        if (i + 2 < NIT) {
            stageA(0, i + 2);
            w0 = loadB(i + 2);
        }
        compute(1);
        if (i + 2 < NIT) {
            vm0();
            flushB(0, w0);
            lgkm0();
        }
    }

    // ---- epilogue: BN + LIF, exact reference op order (4 rows x 8 cols) ----
    if constexpr (MODE == 1) {
#pragma unroll
        for (int i = 0; i < 4; ++i) {
            const int o = o0 + to * 4 + i;
            const float bi = gp.proj_b[o], sc = gp.proj_bn_s[o], bc = gp.proj_bn_b[o];
            float* vr = gp.v_y + (size_t)o * NM + mb;
            const float* xr2 = gp.xT + ((size_t)gp.t * NC + o) * NM + mb;
            float* xyr = gp.xy + (size_t)o * NM + mb;
#pragma unroll
            for (int half = 0; half < 2; ++half) {
                const float4 vld = gp.t ? *(const float4*)(vr + half * 4) : make_float4(0, 0, 0, 0);
                const float4 xv4 = *(const float4*)(xr2 + half * 4);
                float vv[4] = {vld.x, vld.y, vld.z, vld.w};
                const float xvv[4] = {xv4.x, xv4.y, xv4.z, xv4.w};
                float xyo[4];
#pragma unroll
                for (int j = 0; j < 4; ++j) {
                    const float z = __fadd_rn(__fmul_rn(__fadd_rn(acc[i][half * 4 + j], bi), sc), bc);
                    int sp;
                    vv[j] = lif_step(z, vv[j], 1.0f, sp);
                    xyo[j] = __fadd_rn(xvv[j], (float)sp);   // residual x + y
                }
                *(float4*)(vr + half * 4) = make_float4(vv[0], vv[1], vv[2], vv[3]);
                *(float4*)(xyr + half * 4) = make_float4(xyo[0], xyo[1], xyo[2], xyo[3]);
            }
        }
    } else {  // MODE 3
        // 4-aligned halves never straddle a batch boundary (196 % 4 == 0)
        const int b0 = mb / NN,       n0 = mb - b0 * NN;
        const int b1 = (mb + 4) / NN, n1 = (mb + 4) - b1 * NN;
#pragma unroll
        for (int i = 0; i < 4; ++i) {
            const int o = o0 + to * 4 + i;
            const float bi = gp.mlp2_b[o], sc = gp.mlp2_bn_s[o], bc = gp.mlp2_bn_b[o];
            float* vr = gp.v_h2 + (size_t)o * NM + mb;
            const float* xyr = gp.xy + (size_t)o * NM + mb;
#pragma unroll
            for (int half = 0; half < 2; ++half) {
                const float4 vld = gp.t ? *(const float4*)(vr + half * 4) : make_float4(0, 0, 0, 0);
                const float4 xyv = *(const float4*)(xyr + half * 4);
                float vv[4] = {vld.x, vld.y, vld.z, vld.w};
                const float xyf[4] = {xyv.x, xyv.y, xyv.z, xyv.w};
                float ov[4];
#pragma unroll
                for (int j = 0; j < 4; ++j) {
                    const float z = __fadd_rn(__fmul_rn(__fadd_rn(acc[i][half * 4 + j], bi), sc), bc);
                    int sp;
                    vv[j] = lif_step(z, vv[j], 1.0f, sp);
                    ov[j] = __fadd_rn(xyf[j], (float)sp);
                }
                const int b = half ? b1 : b0;
                const int n = half ? n1 : n0;
                *(float4*)&gp.out[(((size_t)gp.t * NB + b) * NC + o) * NN + n] =
                    make_float4(ov[0], ov[1], ov[2], ov[3]);
                *(float4*)(vr + half * 4) = make_float4(vv[0], vv[1], vv[2], vv[3]);
            }
        }
    }
}

extern "C" void kernel_launch(void* const* d_in, const int* in_sizes, int n_in,
                              void* d_out, int out_size, void* d_ws, size_t ws_size,
                              hipStream_t stream) {
    const float* x       = (const float*)d_in[0];
    const float* q_w     = (const float*)d_in[1];
    const float* k_w     = (const float*)d_in[4];
    const float* proj_w  = (const float*)d_in[7];
    const float* mlp1_w  = (const float*)d_in[11];
    const float* mlp2_w  = (const float*)d_in[15];

    GP gp;
    gp.q_bn_s = (const float*)d_in[2];  gp.q_bn_b = (const float*)d_in[3];
    gp.k_bn_s = (const float*)d_in[5];  gp.k_bn_b = (const float*)d_in[6];
    gp.proj_b = (const float*)d_in[8];  gp.proj_bn_s = (const float*)d_in[9];  gp.proj_bn_b = (const float*)d_in[10];
    gp.mlp1_b = (const float*)d_in[12]; gp.mlp1_bn_s = (const float*)d_in[13]; gp.mlp1_bn_b = (const float*)d_in[14];
    gp.mlp2_b = (const float*)d_in[16]; gp.mlp2_bn_s = (const float*)d_in[17]; gp.mlp2_bn_b = (const float*)d_in[18];
    gp.out = (float*)d_out;

    char* ws = (char*)d_ws;
    size_t off = 0;
    auto alloc = [&](size_t bytes) -> void* {
        void* r = ws + off;
        off += (bytes + 255) & ~(size_t)255;
        return r;
    };
    float* wqkT   = (float*)alloc((size_t)512 * 1024 * 4);
    float* wprojT = (float*)alloc((size_t)512 * 512 * 4);
    float* wmlp1T = (float*)alloc((size_t)512 * 2048 * 4);
    float* wmlp2T = (float*)alloc((size_t)2048 * 512 * 4);
    float* xT     = (float*)alloc((size_t)NT * NC * NM * 4);
    gp.xy     = (float*)alloc((size_t)NC * NM * 4);
    gp.v_q    = (float*)alloc((size_t)NC * NM * 4);
    gp.v_k    = (float*)alloc((size_t)NC * NM * 4);
    gp.v_y    = (float*)alloc((size_t)NC * NM * 4);
    gp.v_h2   = (float*)alloc((size_t)NC * NM * 4);
    gp.v_h1   = (float*)alloc((size_t)NCH * NM * 4);
    gp.v_attn = (float*)alloc((size_t)NH * NM * 4);
    gp.q_bt   = (unsigned char*)alloc((size_t)NC * NMB);
    gp.k_bt   = (unsigned char*)alloc((size_t)NC * NMB);
    gp.h1_bt  = (unsigned char*)alloc((size_t)NCH * NMB);
    gp.attn_bt= (unsigned char*)alloc((size_t)NH * NMB);
    gp.wqkT = wqkT; gp.wprojT = wprojT; gp.wmlp1T = wmlp1T; gp.wmlp2T = wmlp2T;
    gp.xT = xT;

    // one-time (per call) layout transforms
    trw_k<<<dim3(16, 16), 256, 0, stream>>>(q_w,    wqkT,   512,  1024, 0);
    trw_k<<<dim3(16, 16), 256, 0, stream>>>(k_w,    wqkT,   512,  1024, 512);
    trw_k<<<dim3(16, 16), 256, 0, stream>>>(proj_w, wprojT, 512,  512,  0);
    trw_k<<<dim3(16, 64), 256, 0, stream>>>(mlp1_w, wmlp1T, 512,  2048, 0);
    trw_k<<<dim3(64, 16), 256, 0, stream>>>(mlp2_w, wmlp2T, 2048, 512,  0);
    permx_k<<<NT * NC * NB, 64, 0, stream>>>(x, xT);

    for (int t = 0; t < NT; ++t) {
        gp.t = t;
        gemm_unf<0><<<dim3(98, 32), 64, 0, stream>>>(gp);   // q,k -> bit-planes
        attn_k<<<dim3(25), 256, 0, stream>>>(gp);           // attn LIF -> bit-plane
        gemm_fus<1><<<dim3(98, 16), 64, 0, stream>>>(gp);   // proj -> v_y, xy
        gemm_unf<2><<<dim3(98, 64), 64, 0, stream>>>(gp);   // mlp1 -> h1 bit-plane
        gemm_fus<3><<<dim3(98, 16), 64, 0, stream>>>(gp);   // mlp2 -> out
    }
}

// Round 15
// 2557.073 us; speedup vs baseline: 6.6094x; 1.0688x over previous
//
#include <hip/hip_runtime.h>
#include <cstdint>

// ---- problem constants ----
#define NT  4
#define NB  32
#define NC  512
#define NCH 2048
#define NN  196
#define NM  (NB * NN)   // 6272 columns = 98*64
#define NMB (NM / 8)    // 784 column-bytes
#define NH  8

struct GP {
    const float *q_bn_s, *q_bn_b, *k_bn_s, *k_bn_b;
    const float *proj_b, *proj_bn_s, *proj_bn_b;
    const float *mlp1_b, *mlp1_bn_s, *mlp1_bn_b;
    const float *mlp2_b, *mlp2_bn_s, *mlp2_bn_b;
    const float *wqkT, *wprojT, *wmlp1T, *wmlp2T;  // [K][O] transposed weights
    const float *xT;                                // [T][C][M] permuted input
    float *xy;                                      // [C][M] x + y_spike (per t)
    float *v_q, *v_k, *v_y, *v_h1, *v_h2, *v_attn;  // LIF states
    // bit-planes [C][NMB]: byte mB holds columns mB*8..mB*8+7 of channel c
    unsigned char *q_bt, *k_bt, *h1_bt, *attn_bt;   // [512/512/2048/8][NMB]
    float *out;
    int t;
};

// Exact-f32 LIF step (bitwise-validated vs reference in R2-R14).
__device__ __forceinline__ float lif_step(float z, float v_old, float vth, int& sp) {
    float d = __fsub_rn(z, v_old);
    float h = __fmul_rn(d, 0.5f);
    float v = __fadd_rn(v_old, h);
    sp = (v >= vth) ? 1 : 0;
    return sp ? 0.0f : v;
}

typedef const void __attribute__((address_space(1))) gas_t;
typedef void __attribute__((address_space(3))) las_t;
__device__ __forceinline__ void gl_lds16(const float* g, float* l) {
    __builtin_amdgcn_global_load_lds((gas_t*)g, (las_t*)l, 16, 0, 0);
}
template <int N>
__device__ __forceinline__ void vmwait() {
    if constexpr (N == 0)      asm volatile("s_waitcnt vmcnt(0)" ::: "memory");
    else if constexpr (N == 3) asm volatile("s_waitcnt vmcnt(3)" ::: "memory");
    else if constexpr (N == 4) asm volatile("s_waitcnt vmcnt(4)" ::: "memory");
}
__device__ __forceinline__ void vm0() {
    asm volatile("s_waitcnt vmcnt(0)" ::: "memory");
}
__device__ __forceinline__ void lgkm0() {
    asm volatile("s_waitcnt lgkmcnt(0)" ::: "memory");
}

// ---------------- pre-kernels ----------------

// dst[c*ldD + offD + o] = src[o*K + c]   (32x32 LDS tiles)
__global__ __launch_bounds__(256) void trw_k(const float* __restrict__ src,
                                             float* __restrict__ dst,
                                             int K, int ldD, int offD) {
    __shared__ float tle[32][33];
    const int c0 = blockIdx.x * 32, o0 = blockIdx.y * 32;
    const int tx = threadIdx.x & 31, ty = threadIdx.x >> 5;
#pragma unroll
    for (int r = 0; r < 4; ++r)
        tle[ty + r * 8][tx] = src[(size_t)(o0 + ty + r * 8) * K + c0 + tx];
    __syncthreads();
#pragma unroll
    for (int r = 0; r < 4; ++r)
        dst[(size_t)(c0 + ty + r * 8) * ldD + offD + o0 + tx] = tle[tx][ty + r * 8];
}

// xT[t][c][b][n] = x[t][b][c][n]
__global__ __launch_bounds__(64) void permx_k(const float* __restrict__ x,
                                              float* __restrict__ xT) {
    const int id = blockIdx.x;         // t*16384 + c*32 + b
    const int b = id & 31;
    const int c = (id >> 5) & 511;
    const int t = id >> 14;
    const float* s = x + ((size_t)(t * NB + b) * NC + c) * NN;
    float* d = xT + ((size_t)(t * NC + c) * NB + b) * NN;
    for (int n = threadIdx.x; n < NN; n += 64) d[n] = s[n];
}

// attn LIF on bit-packed q spikes: thread = (h, column-byte), handles 8 cols.
__global__ __launch_bounds__(256) void attn_k(GP gp) {
    const int id = blockIdx.x * 256 + threadIdx.x;
    if (id >= NH * NMB) return;        // 8*784 = 6272
    const int mB = id % NMB;
    const int h = id / NMB;
    int s[8];
#pragma unroll
    for (int j = 0; j < 8; ++j) s[j] = 0;
    const unsigned char* q = gp.q_bt + (size_t)(h * 64) * NMB + mB;
#pragma unroll 8
    for (int d = 0; d < 64; ++d) {
        const unsigned b = q[(size_t)d * NMB];
#pragma unroll
        for (int j = 0; j < 8; ++j) s[j] += (b >> j) & 1;
    }
    unsigned ob = 0;
#pragma unroll
    for (int j = 0; j < 8; ++j) {
        const int m = mB * 8 + j;
        float v = gp.t ? gp.v_attn[(size_t)h * NM + m] : 0.0f;
        int sp;
        v = lif_step((float)s[j], v, 0.5f, sp);   // dyadic-exact
        gp.v_attn[(size_t)h * NM + m] = v;
        ob |= (unsigned)sp << j;
    }
    gp.attn_bt[(size_t)h * NMB + mB] = (unsigned char)ob;
}

// ---------------- unfused GEMM + BN + LIF (MODE 0 = q&k, MODE 2 = mlp1) ----------------
// R8/R14-proven: 1 wave/block, 2-buffer wave-private LDS, no barriers, vm0 sync.
template <int MODE>
__global__ __launch_bounds__(64) void gemm_unf(GP gp) {
    constexpr int LDA = (MODE == 0) ? 1024 : 2048;
    constexpr int BK = 16;
    constexpr int NIT = 512 / BK;             // 32

    __shared__ float As[2][BK][32];           // 4 KB
    __shared__ float Xs[2][BK][64];           // 8 KB

    const int lane = threadIdx.x;
    const int to = lane & 7;
    const int tn = lane >> 3;
    const int m0 = blockIdx.x * 64;
    const int ot = blockIdx.y;
    const int o0 = ot * 32;
    const int mb = m0 + tn * 8;
    const int mbB = (m0 >> 3) + tn;

    const float* wA = (MODE == 0) ? gp.wqkT : gp.wmlp1T;
    const float* xf = (MODE == 0) ? gp.xT + (size_t)gp.t * NC * NM : gp.xy;

    auto stageA = [&](int buf, int s) {
#pragma unroll
        for (int r = 0; r < 2; ++r)
            gl_lds16(wA + (size_t)(s * BK + r * 8 + (lane >> 3)) * LDA + o0 + (lane & 7) * 4,
                     &As[buf][r * 8][0]);
    };
    auto stageX = [&](int buf, int s) {
#pragma unroll
        for (int r = 0; r < 4; ++r)
            gl_lds16(xf + (size_t)(s * BK + r * 4 + (lane >> 4)) * NM + m0 + (lane & 15) * 4,
                     &Xs[buf][r * 4][0]);
    };

    float acc[4][8];
#pragma unroll
    for (int i = 0; i < 4; ++i)
#pragma unroll
        for (int j = 0; j < 8; ++j) acc[i][j] = 0.0f;

    auto compute = [&](int cur) {
#pragma unroll 4
        for (int kk = 0; kk < BK; ++kk) {
            const float4 av = *(const float4*)&As[cur][kk][to * 4];
            const float4 x0 = *(const float4*)&Xs[cur][kk][tn * 8];
            const float4 x1 = *(const float4*)&Xs[cur][kk][tn * 8 + 4];
            const float a4[4] = {av.x, av.y, av.z, av.w};
            const float x8[8] = {x0.x, x0.y, x0.z, x0.w, x1.x, x1.y, x1.z, x1.w};
#pragma unroll
            for (int i = 0; i < 4; ++i)
#pragma unroll
                for (int j = 0; j < 8; ++j)
                    acc[i][j] = __fadd_rn(acc[i][j], __fmul_rn(a4[i], x8[j]));
        }
    };

    stageA(0, 0); stageX(0, 0);
    vm0();
#pragma unroll 1
    for (int it = 0; it < NIT; ++it) {
        const int cur = it & 1;
        const bool more = (it + 1 < NIT);
        if (more) { stageA(cur ^ 1, it + 1); stageX(cur ^ 1, it + 1); }
        compute(cur);
        if (more) vm0();
    }

    // epilogue: BN + LIF; spike bits -> [C][NMB] planes (1 byte per row)
    if constexpr (MODE == 0) {
        const bool isq = (ot < 16);
        const float* bs = isq ? gp.q_bn_s : gp.k_bn_s;
        const float* bbv = isq ? gp.q_bn_b : gp.k_bn_b;
        float* vb = isq ? gp.v_q : gp.v_k;
        unsigned char* sb = isq ? gp.q_bt : gp.k_bt;
        const int ob = (ot & 15) * 32;
#pragma unroll
        for (int i = 0; i < 4; ++i) {
            const int oo = ob + to * 4 + i;
            const float sc = bs[oo], bc = bbv[oo];
            float* vr = vb + (size_t)oo * NM + mb;
            float vv[8];
            if (gp.t) {
                const float4 v0 = *(const float4*)vr, v1 = *(const float4*)(vr + 4);
                vv[0] = v0.x; vv[1] = v0.y; vv[2] = v0.z; vv[3] = v0.w;
                vv[4] = v1.x; vv[5] = v1.y; vv[6] = v1.z; vv[7] = v1.w;
            } else {
#pragma unroll
                for (int j = 0; j < 8; ++j) vv[j] = 0.0f;
            }
            unsigned pb = 0;
#pragma unroll
            for (int j = 0; j < 8; ++j) {
                const float z = __fadd_rn(__fmul_rn(acc[i][j], sc), bc);
                int sp;
                vv[j] = lif_step(z, vv[j], 1.0f, sp);
                pb |= (unsigned)sp << j;
            }
            *(float4*)vr = make_float4(vv[0], vv[1], vv[2], vv[3]);
            *(float4*)(vr + 4) = make_float4(vv[4], vv[5], vv[6], vv[7]);
            sb[(size_t)oo * NMB + mbB] = (unsigned char)pb;
        }
    } else {
        const int ob = ot * 32;
#pragma unroll
        for (int i = 0; i < 4; ++i) {
            const int o = ob + to * 4 + i;
            const float bi = gp.mlp1_b[o], sc = gp.mlp1_bn_s[o], bc = gp.mlp1_bn_b[o];
            float* vr = gp.v_h1 + (size_t)o * NM + mb;
            float vv[8];
            if (gp.t) {
                const float4 v0 = *(const float4*)vr, v1 = *(const float4*)(vr + 4);
                vv[0] = v0.x; vv[1] = v0.y; vv[2] = v0.z; vv[3] = v0.w;
                vv[4] = v1.x; vv[5] = v1.y; vv[6] = v1.z; vv[7] = v1.w;
            } else {
#pragma unroll
                for (int j = 0; j < 8; ++j) vv[j] = 0.0f;
            }
            unsigned pb = 0;
#pragma unroll
            for (int j = 0; j < 8; ++j) {
                const float z = __fadd_rn(__fmul_rn(__fadd_rn(acc[i][j], bi), sc), bc);
                int sp;
                vv[j] = lif_step(z, vv[j], 1.0f, sp);
                pb |= (unsigned)sp << j;
            }
            *(float4*)vr = make_float4(vv[0], vv[1], vv[2], vv[3]);
            *(float4*)(vr + 4) = make_float4(vv[4], vv[5], vv[6], vv[7]);
            gp.h1_bt[(size_t)o * NMB + mbB] = (unsigned char)pb;
        }
    }
}

// ---------------- fused GEMM + BN + LIF (MODE 1 = proj, MODE 3 = mlp2) ----------------
// R10's PROVEN config restored verbatim: 32o x 32m tile, per-thread 4x4,
// 3136 blocks (12 waves/CU -> latency hidden), 4-buffer LDS ring,
// stage-ahead-2, counted vmcnt, Xs rows padded to 36 floats (0 conflicts).
// Measured in R10: 258 us MODE3 @ 49.8% VALU = at the 2.0 B/FMA LDS cap.
// R14's 4x8 "higher cap" variant lost to grid starvation (1568 blocks,
// 38% VALU) -- block-count arithmetic: 2048 outputs/block => 1568 always.
template <int MODE>
__global__ __launch_bounds__(64) void gemm_fus(GP gp) {
    constexpr int K_TOT = (MODE == 3) ? 2048 : 512;
    constexpr int BK = 16;
    constexpr int NIT = K_TOT / BK;           // 32 or 128 (divisible by 4)
    constexpr int STW = (MODE == 1) ? 4 : 3;  // VM ops per stage

    __shared__ float As[4][BK][32];           // 8 KB
    __shared__ float Xs[4][BK][36];           // 9 KB (padded rows)

    const int lane = threadIdx.x;
    const int to = lane & 7;                  // 4 rows each
    const int tn = lane >> 3;                 // 4 cols each
    const int m0 = blockIdx.x * 32;
    const int o0 = blockIdx.y * 32;
    const int mb = m0 + tn * 4;

    const float* wA = (MODE == 1) ? gp.wprojT : gp.wmlp2T;

    const int xrow = lane >> 2;               // 0..15
    const int xby = lane & 3;                 // byte within 32-col tile
    const int mB8 = (m0 >> 3) + xby;          // global column-byte index

    auto stageA = [&](int buf, int s) {
#pragma unroll
        for (int r = 0; r < 2; ++r)
            gl_lds16(wA + (size_t)(s * BK + r * 8 + (lane >> 3)) * 512 + o0 + (lane & 7) * 4,
                     &As[buf][r * 8][0]);
    };
    auto loadB = [&](int s) -> uint2 {
        const int c = s * BK + xrow;
        uint2 r;
        if constexpr (MODE == 1) {
            r.x = gp.k_bt[(size_t)c * NMB + mB8];
            r.y = gp.attn_bt[(size_t)(c >> 6) * NMB + mB8];
        } else {
            r.x = gp.h1_bt[(size_t)c * NMB + mB8];
            r.y = 0;
        }
        return r;
    };
    auto flushB = [&](int buf, uint2 xb) {
        const unsigned w = (MODE == 1) ? (xb.x & xb.y) : xb.x;  // binary AND == product
        float* d = &Xs[buf][xrow][xby * 8];   // padded row: conflict-free
        float4 f0, f1;
        f0.x = (float)((w) & 1);
        f0.y = (float)((w >> 1) & 1);
        f0.z = (float)((w >> 2) & 1);
        f0.w = (float)((w >> 3) & 1);
        f1.x = (float)((w >> 4) & 1);
        f1.y = (float)((w >> 5) & 1);
        f1.z = (float)((w >> 6) & 1);
        f1.w = (float)((w >> 7) & 1);
        *(float4*)d = f0;
        *(float4*)(d + 4) = f1;
    };

    float acc[4][4];
#pragma unroll
    for (int i = 0; i < 4; ++i)
#pragma unroll
        for (int j = 0; j < 4; ++j) acc[i][j] = 0.0f;

    auto compute = [&](int cb) {
#pragma unroll 8
        for (int kk = 0; kk < BK; ++kk) {
            const float4 av = *(const float4*)&As[cb][kk][to * 4];
            const float4 xv = *(const float4*)&Xs[cb][kk][tn * 4];
            const float a4[4] = {av.x, av.y, av.z, av.w};
            const float x4[4] = {xv.x, xv.y, xv.z, xv.w};
#pragma unroll
            for (int i = 0; i < 4; ++i)
#pragma unroll
                for (int j = 0; j < 4; ++j)
                    acc[i][j] = __fmaf_rn(a4[i], x4[j], acc[i][j]);
        }
    };

    // ---- 4-buffer ring, stage-ahead 2, counted vmcnt (R10-proven) ----
    uint2 sl0, sl1;
    stageA(0, 0); sl0 = loadB(0);
    stageA(1, 1); sl1 = loadB(1);
    vmwait<STW>();                        // stage0 retired (stage1 in flight)
    flushB(0, sl0);
    lgkm0();

    auto body = [&](int i, int cb, uint2& sStage, uint2& sFlush) {
        if (i + 2 < NIT) { stageA((cb + 2) & 3, i + 2); sStage = loadB(i + 2); }
        compute(cb);
        if (i + 1 < NIT) {
            if (NIT - 1 - i >= 2) vmwait<STW>(); else vmwait<0>();
            flushB((cb + 1) & 3, sFlush);
            lgkm0();
        }
    };
#pragma unroll 1
    for (int i = 0; i < NIT; i += 4) {
        body(i + 0, 0, sl0, sl1);
        body(i + 1, 1, sl1, sl0);
        body(i + 2, 2, sl0, sl1);
        body(i + 3, 3, sl1, sl0);
    }

    // ---- epilogue: BN + LIF, exact reference op order (4 rows x 4 cols) ----
    if constexpr (MODE == 1) {
#pragma unroll
        for (int i = 0; i < 4; ++i) {
            const int o = o0 + to * 4 + i;
            const float bi = gp.proj_b[o], sc = gp.proj_bn_s[o], bc = gp.proj_bn_b[o];
            float* vr = gp.v_y + (size_t)o * NM + mb;
            const float4 vld = gp.t ? *(const float4*)vr : make_float4(0, 0, 0, 0);
            const float4 xv4 = *(const float4*)(gp.xT + ((size_t)gp.t * NC + o) * NM + mb);
            float vv[4] = {vld.x, vld.y, vld.z, vld.w};
            const float xvv[4] = {xv4.x, xv4.y, xv4.z, xv4.w};
            float xyo[4];
#pragma unroll
            for (int j = 0; j < 4; ++j) {
                const float z = __fadd_rn(__fmul_rn(__fadd_rn(acc[i][j], bi), sc), bc);
                int sp;
                vv[j] = lif_step(z, vv[j], 1.0f, sp);
                xyo[j] = __fadd_rn(xvv[j], (float)sp);   // residual x + y
            }
            *(float4*)vr = make_float4(vv[0], vv[1], vv[2], vv[3]);
            *(float4*)(gp.xy + (size_t)o * NM + mb) = make_float4(xyo[0], xyo[1], xyo[2], xyo[3]);
        }
    } else {  // MODE 3
        const int b = mb / NN;                // mb%4==0, NN%4==0 -> same b for 4 cols
        const int n = mb - b * NN;
#pragma unroll
        for (int i = 0; i < 4; ++i) {
            const int o = o0 + to * 4 + i;
            const float bi = gp.mlp2_b[o], sc = gp.mlp2_bn_s[o], bc = gp.mlp2_bn_b[o];
            float* vr = gp.v_h2 + (size_t)o * NM + mb;
            const float4 vld = gp.t ? *(const float4*)vr : make_float4(0, 0, 0, 0);
            const float4 xyv = *(const float4*)(gp.xy + (size_t)o * NM + mb);
            float vv[4] = {vld.x, vld.y, vld.z, vld.w};
            const float xyf[4] = {xyv.x, xyv.y, xyv.z, xyv.w};
            float ov[4];
#pragma unroll
            for (int j = 0; j < 4; ++j) {
                const float z = __fadd_rn(__fmul_rn(__fadd_rn(acc[i][j], bi), sc), bc);
                int sp;
                vv[j] = lif_step(z, vv[j], 1.0f, sp);
                ov[j] = __fadd_rn(xyf[j], (float)sp);
            }
            *(float4*)&gp.out[(((size_t)gp.t * NB + b) * NC + o) * NN + n] =
                make_float4(ov[0], ov[1], ov[2], ov[3]);
            *(float4*)vr = make_float4(vv[0], vv[1], vv[2], vv[3]);
        }
    }
}

extern "C" void kernel_launch(void* const* d_in, const int* in_sizes, int n_in,
                              void* d_out, int out_size, void* d_ws, size_t ws_size,
                              hipStream_t stream) {
    const float* x       = (const float*)d_in[0];
    const float* q_w     = (const float*)d_in[1];
    const float* k_w     = (const float*)d_in[4];
    const float* proj_w  = (const float*)d_in[7];
    const float* mlp1_w  = (const float*)d_in[11];
    const float* mlp2_w  = (const float*)d_in[15];

    GP gp;
    gp.q_bn_s = (const float*)d_in[2];  gp.q_bn_b = (const float*)d_in[3];
    gp.k_bn_s = (const float*)d_in[5];  gp.k_bn_b = (const float*)d_in[6];
    gp.proj_b = (const float*)d_in[8];  gp.proj_bn_s = (const float*)d_in[9];  gp.proj_bn_b = (const float*)d_in[10];
    gp.mlp1_b = (const float*)d_in[12]; gp.mlp1_bn_s = (const float*)d_in[13]; gp.mlp1_bn_b = (const float*)d_in[14];
    gp.mlp2_b = (const float*)d_in[16]; gp.mlp2_bn_s = (const float*)d_in[17]; gp.mlp2_bn_b = (const float*)d_in[18];
    gp.out = (float*)d_out;

    char* ws = (char*)d_ws;
    size_t off = 0;
    auto alloc = [&](size_t bytes) -> void* {
        void* r = ws + off;
        off += (bytes + 255) & ~(size_t)255;
        return r;
    };
    float* wqkT   = (float*)alloc((size_t)512 * 1024 * 4);
    float* wprojT = (float*)alloc((size_t)512 * 512 * 4);
    float* wmlp1T = (float*)alloc((size_t)512 * 2048 * 4);
    float* wmlp2T = (float*)alloc((size_t)2048 * 512 * 4);
    float* xT     = (float*)alloc((size_t)NT * NC * NM * 4);
    gp.xy     = (float*)alloc((size_t)NC * NM * 4);
    gp.v_q    = (float*)alloc((size_t)NC * NM * 4);
    gp.v_k    = (float*)alloc((size_t)NC * NM * 4);
    gp.v_y    = (float*)alloc((size_t)NC * NM * 4);
    gp.v_h2   = (float*)alloc((size_t)NC * NM * 4);
    gp.v_h1   = (float*)alloc((size_t)NCH * NM * 4);
    gp.v_attn = (float*)alloc((size_t)NH * NM * 4);
    gp.q_bt   = (unsigned char*)alloc((size_t)NC * NMB);
    gp.k_bt   = (unsigned char*)alloc((size_t)NC * NMB);
    gp.h1_bt  = (unsigned char*)alloc((size_t)NCH * NMB);
    gp.attn_bt= (unsigned char*)alloc((size_t)NH * NMB);
    gp.wqkT = wqkT; gp.wprojT = wprojT; gp.wmlp1T = wmlp1T; gp.wmlp2T = wmlp2T;
    gp.xT = xT;

    // one-time (per call) layout transforms
    trw_k<<<dim3(16, 16), 256, 0, stream>>>(q_w,    wqkT,   512,  1024, 0);
    trw_k<<<dim3(16, 16), 256, 0, stream>>>(k_w,    wqkT,   512,  1024, 512);
    trw_k<<<dim3(16, 16), 256, 0, stream>>>(proj_w, wprojT, 512,  512,  0);
    trw_k<<<dim3(16, 64), 256, 0, stream>>>(mlp1_w, wmlp1T, 512,  2048, 0);
    trw_k<<<dim3(64, 16), 256, 0, stream>>>(mlp2_w, wmlp2T, 2048, 512,  0);
    permx_k<<<NT * NC * NB, 64, 0, stream>>>(x, xT);

    for (int t = 0; t < NT; ++t) {
        gp.t = t;
        gemm_unf<0><<<dim3(98, 32), 64, 0, stream>>>(gp);   // q,k -> bit-planes
        attn_k<<<dim3(25), 256, 0, stream>>>(gp);           // attn LIF -> bit-plane
        gemm_fus<1><<<dim3(196, 16), 64, 0, stream>>>(gp);  // proj -> v_y, xy
        gemm_unf<2><<<dim3(98, 64), 64, 0, stream>>>(gp);   // mlp1 -> h1 bit-plane
        gemm_fus<3><<<dim3(196, 16), 64, 0, stream>>>(gp);  // mlp2 -> out
    }
}